// Round 8
// baseline (503.325 us; speedup 1.0000x reference)
//
#include <hip/hip_runtime.h>
#include <hip/hip_bf16.h>
#include <math.h>

// Problem constants (B=2, L=1024, d_model=1024, d_inner=2048)
constexpr int Bb  = 2;
constexpr int Ls  = 1024;
constexpr int DM  = 1024;   // d_model
constexpr int DI  = 2048;   // d_inner
constexpr int DXZ = 4096;   // 2*d_inner
constexpr int DXD = 96;     // dt_rank + 2*d_state
constexpr int DTR = 64;     // dt_rank
constexpr int DST = 16;     // d_state
constexpr int NCH = 8;      // scan chunks
constexpr int CHL = 128;    // chunk length (NCH*CHL == Ls)
constexpr int ML  = Bb * Ls;   // 2048 rows total

typedef __attribute__((ext_vector_type(8))) short bf16x8;
typedef __attribute__((ext_vector_type(4))) float f32x4;

__device__ __forceinline__ float sigmoidf_(float v) {
    return 1.0f / (1.0f + __expf(-v));
}

// pack two fp32 -> one dword of 2x bf16 (RTNE)
__device__ __forceinline__ int pk_bf16(float lo, float hi) {
    unsigned int ul = __float_as_uint(lo);
    ul += 0x7fffu + ((ul >> 16) & 1u);
    unsigned int uh = __float_as_uint(hi);
    uh += 0x7fffu + ((uh >> 16) & 1u);
    return (int)((ul >> 16) | (uh & 0xffff0000u));
}

// DPP-based sum over each aligned 16-lane group (4 VALU adds, no DS ops).
template <int CTRL>
__device__ __forceinline__ float dpp_add_(float v) {
    int t = __builtin_amdgcn_update_dpp(
        0, __float_as_int(v), CTRL, 0xF, 0xF, true);
    return v + __int_as_float(t);
}
__device__ __forceinline__ float red16_(float p) {
    p = dpp_add_<0xB1>(p);   // quad_perm(1,0,3,2)  : + lane^1
    p = dpp_add_<0x4E>(p);   // quad_perm(2,3,0,1)  : + lane^2
    p = dpp_add_<0x141>(p);  // row_half_mirror     : + other quad in 8
    p = dpp_add_<0x140>(p);  // row_mirror          : + other 8 in 16
    return p;                // all 16 lanes hold the group sum
}

// XOR-swizzled LDS chunk address: tile is [128 rows][4 chunks of 8 bf16].
__device__ __forceinline__ int swz(int row, int chunk) {
    return (((row << 2) + chunk) ^ (row & 7)) << 3;
}

// ---------------------------------------------------------------------------
// bf16 MFMA GEMM with fp32 inputs (in-register convert during staging):
// C[M,N] = A[M,K] @ W[N,K]^T, both fp32 row-major K-contig.
// 128x128 tile, 4 waves (2x2 of 64x64), BK=32. M%128==0, N%128==0, K%32==0.
// SPLIT==1: cols < DI go to C plain; cols >= DI go to C2 with silu applied.
// ---------------------------------------------------------------------------
template <int SPLIT>
__global__ __launch_bounds__(256) void gemm_bf16_f32in(
    const float* __restrict__ A, int lda,
    const float* __restrict__ W, int ldw,
    float* __restrict__ C, float* __restrict__ C2, int ldc, int K)
{
    __shared__ __align__(16) unsigned short As[128 * 32];
    __shared__ __align__(16) unsigned short Ws[128 * 32];

    const int tid  = threadIdx.x;
    const int lane = tid & 63;
    const int wave = tid >> 6;
    const int bm = blockIdx.y * 128;
    const int bn = blockIdx.x * 128;

    const int srow = tid >> 1;
    const int cb   = (tid & 1) * 2;
    const float* Ag = A + (size_t)(bm + srow) * lda + cb * 8;
    const float* Wg = W + (size_t)(bn + srow) * ldw + cb * 8;
    const int ia0 = swz(srow, cb);
    const int ia1 = swz(srow, cb + 1);

    const int wr = (wave >> 1) * 64;
    const int wc = (wave & 1) * 64;
    const int fr = lane & 15;
    const int fq = lane >> 4;

    f32x4 acc[4][4];
#pragma unroll
    for (int m = 0; m < 4; ++m)
#pragma unroll
        for (int n = 0; n < 4; ++n) acc[m][n] = (f32x4){0.f, 0.f, 0.f, 0.f};

    for (int k0 = 0; k0 < K; k0 += 32) {
        const float4 a0 = *(const float4*)(Ag + k0);
        const float4 a1 = *(const float4*)(Ag + k0 + 4);
        const float4 a2 = *(const float4*)(Ag + k0 + 8);
        const float4 a3 = *(const float4*)(Ag + k0 + 12);
        const float4 w0 = *(const float4*)(Wg + k0);
        const float4 w1 = *(const float4*)(Wg + k0 + 4);
        const float4 w2 = *(const float4*)(Wg + k0 + 8);
        const float4 w3 = *(const float4*)(Wg + k0 + 12);

        __syncthreads();
        {
            const int4 pa0 = {pk_bf16(a0.x, a0.y), pk_bf16(a0.z, a0.w),
                              pk_bf16(a1.x, a1.y), pk_bf16(a1.z, a1.w)};
            const int4 pa1 = {pk_bf16(a2.x, a2.y), pk_bf16(a2.z, a2.w),
                              pk_bf16(a3.x, a3.y), pk_bf16(a3.z, a3.w)};
            const int4 pw0 = {pk_bf16(w0.x, w0.y), pk_bf16(w0.z, w0.w),
                              pk_bf16(w1.x, w1.y), pk_bf16(w1.z, w1.w)};
            const int4 pw1 = {pk_bf16(w2.x, w2.y), pk_bf16(w2.z, w2.w),
                              pk_bf16(w3.x, w3.y), pk_bf16(w3.z, w3.w)};
            *(int4*)(As + ia0) = pa0;
            *(int4*)(As + ia1) = pa1;
            *(int4*)(Ws + ia0) = pw0;
            *(int4*)(Ws + ia1) = pw1;
        }
        __syncthreads();

        bf16x8 af[4], bfv[4];
#pragma unroll
        for (int m = 0; m < 4; ++m)
            af[m] = *(const bf16x8*)(As + swz(wr + m * 16 + fr, fq));
#pragma unroll
        for (int n = 0; n < 4; ++n)
            bfv[n] = *(const bf16x8*)(Ws + swz(wc + n * 16 + fr, fq));
#pragma unroll
        for (int m = 0; m < 4; ++m)
#pragma unroll
            for (int n = 0; n < 4; ++n)
                acc[m][n] = __builtin_amdgcn_mfma_f32_16x16x32_bf16(
                    af[m], bfv[n], acc[m][n], 0, 0, 0);
    }

#pragma unroll
    for (int m = 0; m < 4; ++m)
#pragma unroll
        for (int n = 0; n < 4; ++n) {
            const int col = bn + wc + n * 16 + fr;
#pragma unroll
            for (int j = 0; j < 4; ++j) {
                const int row = bm + wr + m * 16 + fq * 4 + j;
                const float v = acc[m][n][j];
                if (SPLIT) {
                    if (col < DI) {
                        C[(size_t)row * ldc + col] = v;
                    } else {
                        C2[(size_t)row * ldc + (col - DI)] = v * sigmoidf_(v);
                    }
                } else {
                    C[(size_t)row * ldc + col] = v;
                }
            }
        }
}

// ---------------------------------------------------------------------------
// Generic fp32 GEMM: C[M,N] = A[M,K] @ W[N,K]^T.
// Split-K via blockIdx.z: A += z*za, W += z*zw, C += z*zc.
// EPI==2: C = softplus(C + bias[row])  (row-indexed bias, for dt_T).
// ---------------------------------------------------------------------------
template <int EPI>
__global__ __launch_bounds__(256) void gemm_nt(
    const float* __restrict__ A, int lda,
    const float* __restrict__ W, int ldw,
    float* __restrict__ C, int ldc,
    int N, int K, const float* __restrict__ bias, int za, int zw, int zc)
{
    A += (size_t)blockIdx.z * za;
    W += (size_t)blockIdx.z * zw;
    C += (size_t)blockIdx.z * zc;

    __shared__ float Asl[16][132];
    __shared__ float Wsl[16][132];

    const int tid = threadIdx.x;
    const int tx = tid & 15;
    const int ty = tid >> 4;
    const int bm = blockIdx.y * 128;
    const int bn = blockIdx.x * 128;

    const int lr = tid >> 1;
    const int lk = (tid & 1) * 8;

    float acc[8][8];
#pragma unroll
    for (int i = 0; i < 8; ++i)
#pragma unroll
        for (int j = 0; j < 8; ++j) acc[i][j] = 0.0f;

    const float* Ap = A + (size_t)(bm + lr) * lda + lk;
    const float* Wp = W + (size_t)(bn + lr) * ldw + lk;
    const bool wok = (bn + lr) < N;
    const float4 f4z = make_float4(0.f, 0.f, 0.f, 0.f);

    for (int k0 = 0; k0 < K; k0 += 16) {
        const float4 av0 = *(const float4*)(Ap + k0);
        const float4 av1 = *(const float4*)(Ap + k0 + 4);
        const float4 wv0 = wok ? *(const float4*)(Wp + k0)     : f4z;
        const float4 wv1 = wok ? *(const float4*)(Wp + k0 + 4) : f4z;

        __syncthreads();
        Asl[lk + 0][lr] = av0.x; Asl[lk + 1][lr] = av0.y;
        Asl[lk + 2][lr] = av0.z; Asl[lk + 3][lr] = av0.w;
        Asl[lk + 4][lr] = av1.x; Asl[lk + 5][lr] = av1.y;
        Asl[lk + 6][lr] = av1.z; Asl[lk + 7][lr] = av1.w;
        Wsl[lk + 0][lr] = wv0.x; Wsl[lk + 1][lr] = wv0.y;
        Wsl[lk + 2][lr] = wv0.z; Wsl[lk + 3][lr] = wv0.w;
        Wsl[lk + 4][lr] = wv1.x; Wsl[lk + 5][lr] = wv1.y;
        Wsl[lk + 6][lr] = wv1.z; Wsl[lk + 7][lr] = wv1.w;
        __syncthreads();

#pragma unroll
        for (int k = 0; k < 16; ++k) {
            const float4 a0 = *(const float4*)&Asl[k][(ty << 2)];
            const float4 a1 = *(const float4*)&Asl[k][64 + (ty << 2)];
            const float4 b0 = *(const float4*)&Wsl[k][(tx << 2)];
            const float4 b1 = *(const float4*)&Wsl[k][64 + (tx << 2)];
            const float ar[8] = {a0.x, a0.y, a0.z, a0.w, a1.x, a1.y, a1.z, a1.w};
            const float br[8] = {b0.x, b0.y, b0.z, b0.w, b1.x, b1.y, b1.z, b1.w};
#pragma unroll
            for (int i = 0; i < 8; ++i)
#pragma unroll
                for (int j = 0; j < 8; ++j)
                    acc[i][j] = fmaf(ar[i], br[j], acc[i][j]);
        }
    }

#pragma unroll
    for (int i = 0; i < 8; ++i) {
        const int row = bm + ((i & 4) << 4) + (ty << 2) + (i & 3);
#pragma unroll
        for (int j = 0; j < 8; ++j) {
            const int col = bn + ((j & 4) << 4) + (tx << 2) + (j & 3);
            if (col < N) {
                float v = acc[i][j];
                if (EPI == 2) {
                    v += bias[row];
                    v = (v > 20.f) ? v : log1pf(__expf(v));
                }
                C[(size_t)row * ldc + col] = v;
            }
        }
    }
}

// ---------------------------------------------------------------------------
// Reduce split-K partials: xdbl[m][j] = sum_kc part[m*768 + kc*96 + j].
// Also scatter-writes the transposed B/C block: bcT[j-64][m] for j>=64.
// ---------------------------------------------------------------------------
__global__ __launch_bounds__(256) void reduce_xdbl_kernel(
    const float* __restrict__ part, float* __restrict__ xdbl,
    float* __restrict__ bcT)
{
    const int idx = blockIdx.x * 256 + threadIdx.x;
    if (idx >= ML * DXD) return;
    const int m = idx / DXD;
    const int j = idx - m * DXD;
    const float* p = part + (size_t)m * 768 + j;
    float s = 0.0f;
#pragma unroll
    for (int kc = 0; kc < 8; ++kc) s += p[kc * DXD];
    xdbl[idx] = s;
    if (j >= DTR) bcT[(size_t)(j - DTR) * ML + m] = s;
}

// ---------------------------------------------------------------------------
// Depthwise causal conv (width 4) + bias + SiLU.  xc [ML][DI] -> xconv.
// ---------------------------------------------------------------------------
__global__ __launch_bounds__(256) void conv_silu_kernel(
    const float* __restrict__ xc,
    const float* __restrict__ conv_w,
    const float* __restrict__ conv_b,
    float* __restrict__ xconv)
{
    const int idx = blockIdx.x * 256 + threadIdx.x;   // over ML*DI
    const int d  = idx & (DI - 1);
    const int bl = idx >> 11;
    const int l  = bl & (Ls - 1);

    const float4 cw = *(const float4*)(conv_w + (d << 2));
    const float w[4] = {cw.x, cw.y, cw.z, cw.w};
    float acc = conv_b[d];
    const float* base = xc + (size_t)bl * DI + d;
#pragma unroll
    for (int j = 0; j < 4; ++j) {
        const int ll = l - 3 + j;
        if (ll >= 0) acc += base[(j - 3) * DI] * w[j];
    }
    xconv[idx] = acc * sigmoidf_(acc);
}

// ---------------------------------------------------------------------------
// Chunked scan pass 1 (chunks 0..NCH-2): per (b,c,d,n) run CHL steps from
// h=0; emit chunk-end state hend and chunk decay exp(Anat * sum(dt)).
// dt/B come from transposed arrays (float4 per 4 steps); x broadcast-loaded.
// ---------------------------------------------------------------------------
__global__ __launch_bounds__(256) void scan_pass1(
    const float* __restrict__ dtT,     // [DI][ML]
    const float* __restrict__ xconv,   // [ML][DI]
    const float* __restrict__ bcT,     // [32][ML]
    const float* __restrict__ A_log,
    float* __restrict__ hend, float* __restrict__ Dprod)
{
    const int b    = blockIdx.z;
    const int c    = blockIdx.y;
    const int lane = threadIdx.x & 63;
    const int wave = threadIdx.x >> 6;
    const int n    = lane & 15;
    const int dl   = lane >> 4;
    const int d    = blockIdx.x * 16 + wave * 4 + dl;
    const int m0   = b * Ls + c * CHL;

    const float Anat = -__expf(A_log[(d << 4) + n]);

    const float4* dtp = (const float4*)(dtT + (size_t)d * ML + m0);
    const float4* Bp  = (const float4*)(bcT + (size_t)n * ML + m0);
    const float*  xq  = xconv + (size_t)m0 * DI + d;

    float4 dt4 = dtp[0], B4 = Bp[0];
    float h = 0.0f, S = 0.0f;

    for (int it = 0; it < CHL / 4; ++it) {
        const float4 dtc = dt4, Bc = B4;
        if (it + 1 < CHL / 4) { dt4 = dtp[it + 1]; B4 = Bp[it + 1]; }
#pragma unroll
        for (int i = 0; i < 4; ++i) {
            const float dtv = ((const float*)&dtc)[i];
            const float Bn  = ((const float*)&Bc)[i];
            const float xv  = *xq; xq += DI;
            S += dtv;
            const float e = __expf(dtv * Anat);
            h = fmaf(e, h, dtv * xv * Bn);
        }
    }

    const size_t idx = (((size_t)(b * NCH + c) * DI + d) << 4) + n;
    hend[idx]  = h;
    Dprod[idx] = __expf(Anat * S);
}

// ---------------------------------------------------------------------------
// Chunked scan pass 2: fold h_init inline (<=7 fma), run CHL steps,
// DPP-reduce y over n, fuse +x*D and the precomputed silu(z) gate.
// Writes y* fp32 in-place over xconv.
// ---------------------------------------------------------------------------
__global__ __launch_bounds__(256) void scan_pass2(
    const float* __restrict__ dtT,     // [DI][ML]
    float* __restrict__ xconv,         // in: x; out: y*  [ML][DI]
    const float* __restrict__ bcT,     // [32][ML]
    const float* __restrict__ zg,      // silu(z) [ML][DI]
    const float* __restrict__ A_log,
    const float* __restrict__ Dp,
    const float* __restrict__ hend, const float* __restrict__ Dprod)
{
    const int b    = blockIdx.z;
    const int c    = blockIdx.y;
    const int lane = threadIdx.x & 63;
    const int wave = threadIdx.x >> 6;
    const int n    = lane & 15;
    const int dl   = lane >> 4;
    const int d    = blockIdx.x * 16 + wave * 4 + dl;
    const int m0   = b * Ls + c * CHL;

    const float Anat = -__expf(A_log[(d << 4) + n]);
    const float dpd  = Dp[d];

    // fold chunk summaries 0..c-1 -> h_init
    float h = 0.0f;
    for (int cp = 0; cp < c; ++cp) {
        const size_t off = (((size_t)(b * NCH + cp) * DI + d) << 4) + n;
        h = fmaf(Dprod[off], h, hend[off]);
    }

    const float4* dtp = (const float4*)(dtT + (size_t)d * ML + m0);
    const float4* Bp  = (const float4*)(bcT + (size_t)n * ML + m0);
    const float4* Cp  = (const float4*)(bcT + (size_t)(DST + n) * ML + m0);
    float* xq = xconv + (size_t)m0 * DI + d;
    const ptrdiff_t zoff = zg - (const float*)xconv;   // constant element offset

    float4 dt4 = dtp[0], B4 = Bp[0], C4 = Cp[0];

    for (int it = 0; it < CHL / 4; ++it) {
        const float4 dtc = dt4, Bc = B4, Cc = C4;
        if (it + 1 < CHL / 4) {
            dt4 = dtp[it + 1]; B4 = Bp[it + 1]; C4 = Cp[it + 1];
        }
#pragma unroll
        for (int i = 0; i < 4; ++i) {
            const float dtv = ((const float*)&dtc)[i];
            const float Bn  = ((const float*)&Bc)[i];
            const float Cn  = ((const float*)&Cc)[i];
            const float xv  = *xq;
            const float e = __expf(dtv * Anat);
            h = fmaf(e, h, dtv * xv * Bn);
            float p = red16_(h * Cn);
            if (n == 0) {
                const float zgv = xq[zoff];
                *xq = fmaf(xv, dpd, p) * zgv;
            }
            xq += DI;
        }
    }
}

// ---------------------------------------------------------------------------
extern "C" void kernel_launch(void* const* d_in, const int* in_sizes, int n_in,
                              void* d_out, int out_size, void* d_ws, size_t ws_size,
                              hipStream_t stream)
{
    const float* x      = (const float*)d_in[0];
    const float* W_in   = (const float*)d_in[1];
    const float* conv_w = (const float*)d_in[2];
    const float* conv_b = (const float*)d_in[3];
    const float* W_x    = (const float*)d_in[4];
    const float* W_dt   = (const float*)d_in[5];
    const float* b_dt   = (const float*)d_in[6];
    const float* A_log  = (const float*)d_in[7];
    const float* Dp     = (const float*)d_in[8];
    const float* W_out  = (const float*)d_in[9];
    float* out = (float*)d_out;

    // workspace (proven 48.75 MB footprint):
    float* ws     = (float*)d_ws;
    float* xc_arr = ws;                         // [2048][2048] 16 MB; later: splitK partials, then dt_T
    float* zg_arr = xc_arr + (size_t)ML * DI;   // [2048][2048] 16 MB silu(z)
    float* xconv  = zg_arr + (size_t)ML * DI;   // [2048][2048] 16 MB x -> y*
    float* xdbl   = xconv  + (size_t)ML * DI;   // [2048][96]  0.75 MB

    // d_out scratch (dead until the final GEMM): 4.25 MB of 8 MB
    float* hend  = out;                                   // [Bb*NCH*DI*16] 2 MB
    float* Dprod = hend + (size_t)Bb * NCH * DI * DST;    // 2 MB
    float* bcT   = Dprod + (size_t)Bb * NCH * DI * DST;   // [32][2048] 0.25 MB

    float* dtT   = xc_arr;   // dt_T [DI][ML] overwrites dead xc region
    const dim3 blk(256);

    // 1) in-proj: xc | silu(z) = x @ W_in^T   (bf16 MFMA, split epilogue)
    gemm_bf16_f32in<1><<<dim3(DXZ / 128, ML / 128), blk, 0, stream>>>(
        x, DM, W_in, DM, xc_arr, zg_arr, DI, DM);

    // 2) depthwise causal conv + silu -> xconv
    conv_silu_kernel<<<dim3((ML * DI) / 256), blk, 0, stream>>>(
        xc_arr, conv_w, conv_b, xconv);

    // 3) x_dbl partials = xconv @ W_x^T (fp32, split-K x8) -> xc_arr (dead)
    gemm_nt<0><<<dim3(1, ML / 128, 8), blk, 0, stream>>>(
        xconv, DI, W_x, DI, xc_arr, 768, DXD, DI / 8, nullptr,
        DI / 8, DI / 8, DXD);
    reduce_xdbl_kernel<<<dim3((ML * DXD + 255) / 256), blk, 0, stream>>>(
        xc_arr, xdbl, bcT);

    // 4) dt_T = softplus(W_dt @ x_dbl[:, :64]^T + b_dt[row])  [DI][ML]
    gemm_nt<2><<<dim3(ML / 128, DI / 128), blk, 0, stream>>>(
        W_dt, DTR, xdbl, DXD, dtT, ML, ML, DTR, b_dt, 0, 0, 0);

    // 5) chunked selective scan -> y* in-place over xconv
    scan_pass1<<<dim3(DI / 16, NCH - 1, Bb), blk, 0, stream>>>(
        dtT, xconv, bcT, A_log, hend, Dprod);
    scan_pass2<<<dim3(DI / 16, NCH, Bb), blk, 0, stream>>>(
        dtT, xconv, bcT, zg_arr, A_log, Dp, hend, Dprod);

    // 6) out = y* @ W_out^T  (bf16 MFMA)  M=2048 N=1024 K=2048
    gemm_bf16_f32in<0><<<dim3(DM / 128, ML / 128), blk, 0, stream>>>(
        xconv, DI, W_out, DI, out, nullptr, DM, DI);
}

// Round 9
// 446.787 us; speedup vs baseline: 1.1265x; 1.1265x over previous
//
#include <hip/hip_runtime.h>
#include <hip/hip_bf16.h>
#include <math.h>

// Problem constants (B=2, L=1024, d_model=1024, d_inner=2048)
constexpr int Bb  = 2;
constexpr int Ls  = 1024;
constexpr int DM  = 1024;   // d_model
constexpr int DI  = 2048;   // d_inner
constexpr int DXZ = 4096;   // 2*d_inner
constexpr int DXD = 96;     // dt_rank + 2*d_state
constexpr int DTR = 64;     // dt_rank
constexpr int DST = 16;     // d_state
constexpr int NCH = 8;      // scan chunks
constexpr int CHL = 128;    // chunk length (NCH*CHL == Ls)
constexpr int ML  = Bb * Ls;   // 2048 rows total

typedef __attribute__((ext_vector_type(8))) short bf16x8;
typedef __attribute__((ext_vector_type(4))) float f32x4;

__device__ __forceinline__ float sigmoidf_(float v) {
    return 1.0f / (1.0f + __expf(-v));
}

// pack two fp32 -> one dword of 2x bf16 (RTNE)
__device__ __forceinline__ int pk_bf16(float lo, float hi) {
    unsigned int ul = __float_as_uint(lo);
    ul += 0x7fffu + ((ul >> 16) & 1u);
    unsigned int uh = __float_as_uint(hi);
    uh += 0x7fffu + ((uh >> 16) & 1u);
    return (int)((ul >> 16) | (uh & 0xffff0000u));
}

// DPP-based sum over each aligned 16-lane group (4 VALU adds, no DS ops).
template <int CTRL>
__device__ __forceinline__ float dpp_add_(float v) {
    int t = __builtin_amdgcn_update_dpp(
        0, __float_as_int(v), CTRL, 0xF, 0xF, true);
    return v + __int_as_float(t);
}
__device__ __forceinline__ float red16_(float p) {
    p = dpp_add_<0xB1>(p);   // quad_perm(1,0,3,2)  : + lane^1
    p = dpp_add_<0x4E>(p);   // quad_perm(2,3,0,1)  : + lane^2
    p = dpp_add_<0x141>(p);  // row_half_mirror     : + other quad in 8
    p = dpp_add_<0x140>(p);  // row_mirror          : + other 8 in 16
    return p;                // all 16 lanes hold the group sum
}

// XOR-swizzled LDS chunk address: tile is [128 rows][4 chunks of 8 bf16].
__device__ __forceinline__ int swz(int row, int chunk) {
    return (((row << 2) + chunk) ^ (row & 7)) << 3;
}

// ---------------------------------------------------------------------------
// bf16 MFMA GEMM: C[M,N] = A[M,K] @ W[N,K]^T. W fp32 (packed in staging).
// ABF16==0: A fp32, packed in staging. ABF16==1: A already bf16 [M][K].
// 128x128 tile, 4 waves (2x2 of 64x64), BK=32. M%128==0, N%128==0, K%32==0.
// SPLIT==1: cols < DI -> C plain; cols >= DI -> C2 with silu applied.
// ---------------------------------------------------------------------------
template <int SPLIT, int ABF16>
__global__ __launch_bounds__(256) void gemm_bf16_f32in(
    const void* __restrict__ Av, int lda,
    const float* __restrict__ W, int ldw,
    float* __restrict__ C, float* __restrict__ C2, int ldc, int K)
{
    __shared__ __align__(16) unsigned short As[128 * 32];
    __shared__ __align__(16) unsigned short Ws[128 * 32];

    const int tid  = threadIdx.x;
    const int lane = tid & 63;
    const int wave = tid >> 6;
    const int bm = blockIdx.y * 128;
    const int bn = blockIdx.x * 128;

    const int srow = tid >> 1;
    const int cb   = (tid & 1) * 2;
    const float* Ag = (ABF16 ? nullptr
                             : (const float*)Av + (size_t)(bm + srow) * lda + cb * 8);
    const unsigned short* Ag16 = (ABF16
        ? (const unsigned short*)Av + (size_t)(bm + srow) * lda + cb * 8 : nullptr);
    const float* Wg = W + (size_t)(bn + srow) * ldw + cb * 8;
    const int ia0 = swz(srow, cb);
    const int ia1 = swz(srow, cb + 1);

    const int wr = (wave >> 1) * 64;
    const int wc = (wave & 1) * 64;
    const int fr = lane & 15;
    const int fq = lane >> 4;

    f32x4 acc[4][4];
#pragma unroll
    for (int m = 0; m < 4; ++m)
#pragma unroll
        for (int n = 0; n < 4; ++n) acc[m][n] = (f32x4){0.f, 0.f, 0.f, 0.f};

    for (int k0 = 0; k0 < K; k0 += 32) {
        int4 pa0, pa1;
        if (ABF16) {
            pa0 = *(const int4*)(Ag16 + k0);
            pa1 = *(const int4*)(Ag16 + k0 + 8);
        } else {
            const float4 a0 = *(const float4*)(Ag + k0);
            const float4 a1 = *(const float4*)(Ag + k0 + 4);
            const float4 a2 = *(const float4*)(Ag + k0 + 8);
            const float4 a3 = *(const float4*)(Ag + k0 + 12);
            pa0 = (int4){pk_bf16(a0.x, a0.y), pk_bf16(a0.z, a0.w),
                         pk_bf16(a1.x, a1.y), pk_bf16(a1.z, a1.w)};
            pa1 = (int4){pk_bf16(a2.x, a2.y), pk_bf16(a2.z, a2.w),
                         pk_bf16(a3.x, a3.y), pk_bf16(a3.z, a3.w)};
        }
        const float4 w0 = *(const float4*)(Wg + k0);
        const float4 w1 = *(const float4*)(Wg + k0 + 4);
        const float4 w2 = *(const float4*)(Wg + k0 + 8);
        const float4 w3 = *(const float4*)(Wg + k0 + 12);

        __syncthreads();
        {
            const int4 pw0 = {pk_bf16(w0.x, w0.y), pk_bf16(w0.z, w0.w),
                              pk_bf16(w1.x, w1.y), pk_bf16(w1.z, w1.w)};
            const int4 pw1 = {pk_bf16(w2.x, w2.y), pk_bf16(w2.z, w2.w),
                              pk_bf16(w3.x, w3.y), pk_bf16(w3.z, w3.w)};
            *(int4*)(As + ia0) = pa0;
            *(int4*)(As + ia1) = pa1;
            *(int4*)(Ws + ia0) = pw0;
            *(int4*)(Ws + ia1) = pw1;
        }
        __syncthreads();

        bf16x8 af[4], bfv[4];
#pragma unroll
        for (int m = 0; m < 4; ++m)
            af[m] = *(const bf16x8*)(As + swz(wr + m * 16 + fr, fq));
#pragma unroll
        for (int n = 0; n < 4; ++n)
            bfv[n] = *(const bf16x8*)(Ws + swz(wc + n * 16 + fr, fq));
#pragma unroll
        for (int m = 0; m < 4; ++m)
#pragma unroll
            for (int n = 0; n < 4; ++n)
                acc[m][n] = __builtin_amdgcn_mfma_f32_16x16x32_bf16(
                    af[m], bfv[n], acc[m][n], 0, 0, 0);
    }

#pragma unroll
    for (int m = 0; m < 4; ++m)
#pragma unroll
        for (int n = 0; n < 4; ++n) {
            const int col = bn + wc + n * 16 + fr;
#pragma unroll
            for (int j = 0; j < 4; ++j) {
                const int row = bm + wr + m * 16 + fq * 4 + j;
                const float v = acc[m][n][j];
                if (SPLIT) {
                    if (col < DI) {
                        C[(size_t)row * ldc + col] = v;
                    } else {
                        C2[(size_t)row * ldc + (col - DI)] = v * sigmoidf_(v);
                    }
                } else {
                    C[(size_t)row * ldc + col] = v;
                }
            }
        }
}

// ---------------------------------------------------------------------------
// Generic fp32 GEMM: C[M,N] = A[M,K] @ W[N,K]^T.
// ATRANS==1: A is stored transposed [K][M] (row stride lda=M-dim stride);
//            staging reads k-rows m-contiguous (for xT source).
// Split-K via blockIdx.z: A += z*za, W += z*zw, C += z*zc.
// EPI==2: C = softplus(C + bias[row]).
// ---------------------------------------------------------------------------
template <int EPI, int ATRANS>
__global__ __launch_bounds__(256) void gemm_nt(
    const float* __restrict__ A, int lda,
    const float* __restrict__ W, int ldw,
    float* __restrict__ C, int ldc,
    int N, int K, const float* __restrict__ bias, int za, int zw, int zc)
{
    A += (size_t)blockIdx.z * za;
    W += (size_t)blockIdx.z * zw;
    C += (size_t)blockIdx.z * zc;

    __shared__ float Asl[16][132];
    __shared__ float Wsl[16][132];

    const int tid = threadIdx.x;
    const int tx = tid & 15;
    const int ty = tid >> 4;
    const int bm = blockIdx.y * 128;
    const int bn = blockIdx.x * 128;

    const int lr = tid >> 1;
    const int lk = (tid & 1) * 8;
    // ATRANS staging map
    const int krow = tid >> 4;          // 0..15
    const int mseg = (tid & 15) * 8;

    float acc[8][8];
#pragma unroll
    for (int i = 0; i < 8; ++i)
#pragma unroll
        for (int j = 0; j < 8; ++j) acc[i][j] = 0.0f;

    const float* Ap = ATRANS
        ? A + (size_t)krow * lda + bm + mseg
        : A + (size_t)(bm + lr) * lda + lk;
    const float* Wp = W + (size_t)(bn + lr) * ldw + lk;
    const bool wok = (bn + lr) < N;
    const float4 f4z = make_float4(0.f, 0.f, 0.f, 0.f);

    for (int k0 = 0; k0 < K; k0 += 16) {
        float4 av0, av1;
        if (ATRANS) {
            av0 = *(const float4*)(Ap + (size_t)k0 * lda);
            av1 = *(const float4*)(Ap + (size_t)k0 * lda + 4);
        } else {
            av0 = *(const float4*)(Ap + k0);
            av1 = *(const float4*)(Ap + k0 + 4);
        }
        const float4 wv0 = wok ? *(const float4*)(Wp + k0)     : f4z;
        const float4 wv1 = wok ? *(const float4*)(Wp + k0 + 4) : f4z;

        __syncthreads();
        if (ATRANS) {
            *(float4*)&Asl[krow][mseg]     = av0;
            *(float4*)&Asl[krow][mseg + 4] = av1;
        } else {
            Asl[lk + 0][lr] = av0.x; Asl[lk + 1][lr] = av0.y;
            Asl[lk + 2][lr] = av0.z; Asl[lk + 3][lr] = av0.w;
            Asl[lk + 4][lr] = av1.x; Asl[lk + 5][lr] = av1.y;
            Asl[lk + 6][lr] = av1.z; Asl[lk + 7][lr] = av1.w;
        }
        Wsl[lk + 0][lr] = wv0.x; Wsl[lk + 1][lr] = wv0.y;
        Wsl[lk + 2][lr] = wv0.z; Wsl[lk + 3][lr] = wv0.w;
        Wsl[lk + 4][lr] = wv1.x; Wsl[lk + 5][lr] = wv1.y;
        Wsl[lk + 6][lr] = wv1.z; Wsl[lk + 7][lr] = wv1.w;
        __syncthreads();

#pragma unroll
        for (int k = 0; k < 16; ++k) {
            const float4 a0 = *(const float4*)&Asl[k][(ty << 2)];
            const float4 a1 = *(const float4*)&Asl[k][64 + (ty << 2)];
            const float4 b0 = *(const float4*)&Wsl[k][(tx << 2)];
            const float4 b1 = *(const float4*)&Wsl[k][64 + (tx << 2)];
            const float ar[8] = {a0.x, a0.y, a0.z, a0.w, a1.x, a1.y, a1.z, a1.w};
            const float br[8] = {b0.x, b0.y, b0.z, b0.w, b1.x, b1.y, b1.z, b1.w};
#pragma unroll
            for (int i = 0; i < 8; ++i)
#pragma unroll
                for (int j = 0; j < 8; ++j)
                    acc[i][j] = fmaf(ar[i], br[j], acc[i][j]);
        }
    }

#pragma unroll
    for (int i = 0; i < 8; ++i) {
        const int row = bm + ((i & 4) << 4) + (ty << 2) + (i & 3);
#pragma unroll
        for (int j = 0; j < 8; ++j) {
            const int col = bn + ((j & 4) << 4) + (tx << 2) + (j & 3);
            if (col < N) {
                float v = acc[i][j];
                if (EPI == 2) {
                    v += bias[row];
                    v = (v > 20.f) ? v : log1pf(__expf(v));
                }
                C[(size_t)row * ldc + col] = v;
            }
        }
    }
}

// ---------------------------------------------------------------------------
// Reduce split-K partials: xdbl[m][j] = sum_kc part[m*768 + kc*96 + j].
// Also scatter-writes the transposed B/C block: bcT[j-64][m] for j>=64.
// ---------------------------------------------------------------------------
__global__ __launch_bounds__(256) void reduce_xdbl_kernel(
    const float* __restrict__ part, float* __restrict__ xdbl,
    float* __restrict__ bcT)
{
    const int idx = blockIdx.x * 256 + threadIdx.x;
    if (idx >= ML * DXD) return;
    const int m = idx / DXD;
    const int j = idx - m * DXD;
    const float* p = part + (size_t)m * 768 + j;
    float s = 0.0f;
#pragma unroll
    for (int kc = 0; kc < 8; ++kc) s += p[kc * DXD];
    xdbl[idx] = s;
    if (j >= DTR) bcT[(size_t)(j - DTR) * ML + m] = s;
}

// ---------------------------------------------------------------------------
// Depthwise causal conv (width 4) + bias + SiLU, TRANSPOSING output:
// reads xc[m][d] tiles (coalesced, +3 halo rows), writes xT[d][m] (coalesced).
// Block: 32 d x 256 m.
// ---------------------------------------------------------------------------
constexpr int CT_LDS = 260;   // LDS row stride (words); mult of 4, 259 used
__global__ __launch_bounds__(256) void conv_transpose_kernel(
    const float* __restrict__ xc,
    const float* __restrict__ conv_w,
    const float* __restrict__ conv_b,
    float* __restrict__ xT)
{
    __shared__ float tile[32][CT_LDS];
    const int d0 = blockIdx.x * 32;
    const int m0 = blockIdx.y * 256;
    const int t  = threadIdx.x;
    const bool atStart = ((m0 & (Ls - 1)) == 0);

    // load rows r=-3..255  ->  tile[d][3+r]
    for (int rg = 0; rg < 33; ++rg) {
        const int r = rg * 8 + (t >> 5) - 3;
        const int dcol = t & 31;
        if (r <= 255) {
            float v = 0.0f;
            if (r >= 0 || !atStart)
                v = xc[(size_t)(m0 + r) * DI + d0 + dcol];
            tile[dcol][3 + r] = v;
        }
    }
    __syncthreads();

    const int dd  = t >> 3;
    const int seg = (t & 7) * 32;
    const int d   = d0 + dd;
    const float4 cw = *(const float4*)(conv_w + (d << 2));
    const float  cb = conv_b[d];
    float* dst = xT + (size_t)d * ML + m0 + seg;

    float4 cur = *(const float4*)&tile[dd][seg];   // x[m-3..m] for first out
#pragma unroll
    for (int g = 0; g < 8; ++g) {
        const float4 nxt = *(const float4*)&tile[dd][seg + 4 * g + 4];
        const float a0 = cb + cw.x*cur.x + cw.y*cur.y + cw.z*cur.z + cw.w*cur.w;
        const float a1 = cb + cw.x*cur.y + cw.y*cur.z + cw.z*cur.w + cw.w*nxt.x;
        const float a2 = cb + cw.x*cur.z + cw.y*cur.w + cw.z*nxt.x + cw.w*nxt.y;
        const float a3 = cb + cw.x*cur.w + cw.y*nxt.x + cw.z*nxt.y + cw.w*nxt.z;
        float4 o;
        o.x = a0 * sigmoidf_(a0); o.y = a1 * sigmoidf_(a1);
        o.z = a2 * sigmoidf_(a2); o.w = a3 * sigmoidf_(a3);
        *(float4*)(dst + 4 * g) = o;
        cur = nxt;
    }
}

// ---------------------------------------------------------------------------
// Chunked scan pass 1 (chunks 0..NCH-2): per (b,c,d,n) run CHL steps from
// h=0; emit chunk-end state hend and chunk decay exp(Anat * sum(dt)).
// ALL streams [*][m]-contiguous (float4 per 4 steps).
// ---------------------------------------------------------------------------
__global__ __launch_bounds__(256) void scan_pass1(
    const float* __restrict__ dtT,     // [DI][ML]
    const float* __restrict__ xT,      // [DI][ML]
    const float* __restrict__ bcT,     // [32][ML]
    const float* __restrict__ A_log,
    float* __restrict__ hend, float* __restrict__ Dprod)
{
    const int b    = blockIdx.z;
    const int c    = blockIdx.y;
    const int lane = threadIdx.x & 63;
    const int wave = threadIdx.x >> 6;
    const int n    = lane & 15;
    const int dl   = lane >> 4;
    const int d    = blockIdx.x * 16 + wave * 4 + dl;
    const int m0   = b * Ls + c * CHL;

    const float Anat = -__expf(A_log[(d << 4) + n]);

    const float4* dtp = (const float4*)(dtT + (size_t)d * ML + m0);
    const float4* xp  = (const float4*)(xT  + (size_t)d * ML + m0);
    const float4* Bp  = (const float4*)(bcT + (size_t)n * ML + m0);

    float4 dt4 = dtp[0], x4 = xp[0], B4 = Bp[0];
    float h = 0.0f, S = 0.0f;

    for (int it = 0; it < CHL / 4; ++it) {
        const float4 dtc = dt4, xc4 = x4, Bc = B4;
        if (it + 1 < CHL / 4) {
            dt4 = dtp[it + 1]; x4 = xp[it + 1]; B4 = Bp[it + 1];
        }
#pragma unroll
        for (int i = 0; i < 4; ++i) {
            const float dtv = ((const float*)&dtc)[i];
            const float xv  = ((const float*)&xc4)[i];
            const float Bn  = ((const float*)&Bc)[i];
            S += dtv;
            const float e = __expf(dtv * Anat);
            h = fmaf(e, h, dtv * xv * Bn);
        }
    }

    const size_t idx = (((size_t)(b * NCH + c) * DI + d) << 4) + n;
    hend[idx]  = h;
    Dprod[idx] = __expf(Anat * S);
}

// ---------------------------------------------------------------------------
// Chunked scan pass 2: fold h_init inline, run CHL steps, DPP-reduce y over
// n, add x*D. Writes ungated yT IN-PLACE over xT (block owns its cells).
// ---------------------------------------------------------------------------
__global__ __launch_bounds__(256) void scan_pass2(
    const float* __restrict__ dtT,     // [DI][ML]
    float* xT,                          // in: x, out: yT (in-place, no restrict)
    const float* __restrict__ bcT,     // [32][ML]
    const float* __restrict__ A_log,
    const float* __restrict__ Dp,
    const float* __restrict__ hend, const float* __restrict__ Dprod)
{
    const int b    = blockIdx.z;
    const int c    = blockIdx.y;
    const int lane = threadIdx.x & 63;
    const int wave = threadIdx.x >> 6;
    const int n    = lane & 15;
    const int dl   = lane >> 4;
    const int d    = blockIdx.x * 16 + wave * 4 + dl;
    const int m0   = b * Ls + c * CHL;

    const float Anat = -__expf(A_log[(d << 4) + n]);
    const float dpd  = Dp[d];

    // fold chunk summaries 0..c-1 -> h_init
    float h = 0.0f;
    for (int cp = 0; cp < c; ++cp) {
        const size_t off = (((size_t)(b * NCH + cp) * DI + d) << 4) + n;
        h = fmaf(Dprod[off], h, hend[off]);
    }

    const float4* dtp = (const float4*)(dtT + (size_t)d * ML + m0);
    const float4* xp  = (const float4*)(xT  + (size_t)d * ML + m0);
    const float4* Bp  = (const float4*)(bcT + (size_t)n * ML + m0);
    const float4* Cp  = (const float4*)(bcT + (size_t)(DST + n) * ML + m0);
    float4* yq = (float4*)(xT + (size_t)d * ML + m0);

    float4 dt4 = dtp[0], x4 = xp[0], B4 = Bp[0], C4 = Cp[0];

    for (int it = 0; it < CHL / 4; ++it) {
        const float4 dtc = dt4, xc4 = x4, Bc = B4, Cc = C4;
        if (it + 1 < CHL / 4) {
            dt4 = dtp[it + 1]; x4 = xp[it + 1];
            B4 = Bp[it + 1];   C4 = Cp[it + 1];
        }
        float4 y4;
#pragma unroll
        for (int i = 0; i < 4; ++i) {
            const float dtv = ((const float*)&dtc)[i];
            const float xv  = ((const float*)&xc4)[i];
            const float Bn  = ((const float*)&Bc)[i];
            const float Cn  = ((const float*)&Cc)[i];
            const float e = __expf(dtv * Anat);
            h = fmaf(e, h, dtv * xv * Bn);
            const float p = red16_(h * Cn);
            ((float*)&y4)[i] = fmaf(xv, dpd, p);
        }
        if (n == 0) yq[it] = y4;    // coalesced-per-row float4, disjoint cells
    }
}

// ---------------------------------------------------------------------------
// Gate + transpose: y_bf16[m][d] = bf16( yT[d][m] * zg[m][d] ).
// Both reads coalesced in their own layouts via two LDS tiles (64x64).
// ---------------------------------------------------------------------------
__global__ __launch_bounds__(256) void gate_transpose_kernel(
    const float* __restrict__ yT,       // [DI][ML]
    const float* __restrict__ zg,       // [ML][DI]  (silu already applied)
    unsigned short* __restrict__ yb)    // [ML][DI] bf16
{
    __shared__ float Ty[64][65];
    __shared__ float Tz[64][65];
    const int d0 = blockIdx.x * 64;
    const int m0 = blockIdx.y * 64;
    const int t  = threadIdx.x;
    const int cc = t & 63, r4 = t >> 6;

#pragma unroll 4
    for (int rr = 0; rr < 16; ++rr) {
        const int r = rr * 4 + r4;
        Ty[r][cc] = yT[(size_t)(d0 + r) * ML + m0 + cc];
        Tz[r][cc] = zg[(size_t)(m0 + r) * DI + d0 + cc];
    }
    __syncthreads();

    const int dp  = (t & 31) * 2;
    const int mr4 = t >> 5;
#pragma unroll 4
    for (int rr = 0; rr < 8; ++rr) {
        const int mr = rr * 8 + mr4;
        const float v0 = Ty[dp][mr]     * Tz[mr][dp];
        const float v1 = Ty[dp + 1][mr] * Tz[mr][dp + 1];
        *(unsigned int*)(yb + (size_t)(m0 + mr) * DI + d0 + dp) =
            (unsigned int)pk_bf16(v0, v1);
    }
}

// ---------------------------------------------------------------------------
extern "C" void kernel_launch(void* const* d_in, const int* in_sizes, int n_in,
                              void* d_out, int out_size, void* d_ws, size_t ws_size,
                              hipStream_t stream)
{
    const float* x      = (const float*)d_in[0];
    const float* W_in   = (const float*)d_in[1];
    const float* conv_w = (const float*)d_in[2];
    const float* conv_b = (const float*)d_in[3];
    const float* W_x    = (const float*)d_in[4];
    const float* W_dt   = (const float*)d_in[5];
    const float* b_dt   = (const float*)d_in[6];
    const float* A_log  = (const float*)d_in[7];
    const float* Dp     = (const float*)d_in[8];
    const float* W_out  = (const float*)d_in[9];
    float* out = (float*)d_out;

    // workspace (proven 48.75 MB footprint):
    float* ws     = (float*)d_ws;
    float* xc_arr = ws;                         // 16 MB: xc -> splitK partials -> dtT -> y_bf16
    float* zg_arr = xc_arr + (size_t)ML * DI;   // 16 MB: silu(z) [m][d]
    float* xT_arr = zg_arr + (size_t)ML * DI;   // 16 MB: xT[d][m] -> yT in-place
    float* xdbl   = xT_arr + (size_t)ML * DI;   // 0.75 MB

    // d_out scratch (dead until gate/out-GEMM): 4.25 MB of 8 MB
    float* hend  = out;                                   // 2 MB
    float* Dprod = hend + (size_t)Bb * NCH * DI * DST;    // 2 MB
    float* bcT   = Dprod + (size_t)Bb * NCH * DI * DST;   // [32][2048] 0.25 MB

    float* dtT = xc_arr;                                  // [DI][ML] over xc
    unsigned short* ybf = (unsigned short*)xc_arr;        // bf16 y[m][d], 8 MB

    const dim3 blk(256);

    // 1) in-proj: xc | silu(z) = x @ W_in^T   (bf16 MFMA, split epilogue)
    gemm_bf16_f32in<1, 0><<<dim3(DXZ / 128, ML / 128), blk, 0, stream>>>(
        x, DM, W_in, DM, xc_arr, zg_arr, DI, DM);

    // 2) depthwise causal conv + silu, transposed -> xT[d][m]
    conv_transpose_kernel<<<dim3(DI / 32, ML / 256), blk, 0, stream>>>(
        xc_arr, conv_w, conv_b, xT_arr);

    // 3) x_dbl partials = x @ W_x^T from xT (ATRANS, split-K x8) -> xc (dead)
    gemm_nt<0, 1><<<dim3(1, ML / 128, 8), blk, 0, stream>>>(
        xT_arr, ML, W_x, DI, xc_arr, 768, DXD, DI / 8, nullptr,
        (DI / 8) * ML, DI / 8, DXD);
    reduce_xdbl_kernel<<<dim3((ML * DXD + 255) / 256), blk, 0, stream>>>(
        xc_arr, xdbl, bcT);

    // 4) dt_T = softplus(W_dt @ x_dbl[:, :64]^T + b_dt[row])  [DI][ML] over xc
    gemm_nt<2, 0><<<dim3(ML / 128, DI / 128), blk, 0, stream>>>(
        W_dt, DTR, xdbl, DXD, dtT, ML, ML, DTR, b_dt, 0, 0, 0);

    // 5) chunked selective scan; pass2 writes ungated yT in-place over xT
    scan_pass1<<<dim3(DI / 16, NCH - 1, Bb), blk, 0, stream>>>(
        dtT, xT_arr, bcT, A_log, hend, Dprod);
    scan_pass2<<<dim3(DI / 16, NCH, Bb), blk, 0, stream>>>(
        dtT, xT_arr, bcT, A_log, Dp, hend, Dprod);

    // 6) gate + transpose: y_bf16[m][d] = yT * silu(z)   (dtT now dead)
    gate_transpose_kernel<<<dim3(DI / 64, ML / 64), blk, 0, stream>>>(
        xT_arr, zg_arr, ybf);

    // 7) out = y_bf16 @ W_out^T  (bf16-A MFMA)  M=2048 N=1024 K=2048
    gemm_bf16_f32in<0, 1><<<dim3(DM / 128, ML / 128), blk, 0, stream>>>(
        ybf, DI, W_out, DI, out, nullptr, DM, DI);
}

// Round 10
// 411.342 us; speedup vs baseline: 1.2236x; 1.0862x over previous
//
#include <hip/hip_runtime.h>
#include <hip/hip_bf16.h>
#include <math.h>

// Problem constants (B=2, L=1024, d_model=1024, d_inner=2048)
constexpr int Bb  = 2;
constexpr int Ls  = 1024;
constexpr int DM  = 1024;   // d_model
constexpr int DI  = 2048;   // d_inner
constexpr int DXZ = 4096;   // 2*d_inner
constexpr int DXD = 96;     // dt_rank + 2*d_state
constexpr int DTR = 64;     // dt_rank
constexpr int DST = 16;     // d_state
constexpr int NCH = 8;      // scan chunks
constexpr int CHL = 128;    // chunk length (NCH*CHL == Ls)
constexpr int ML  = Bb * Ls;   // 2048 rows total

typedef __attribute__((ext_vector_type(8))) short bf16x8;
typedef __attribute__((ext_vector_type(4))) float f32x4;

__device__ __forceinline__ float sigmoidf_(float v) {
    return 1.0f / (1.0f + __expf(-v));
}

// pack two fp32 -> one dword of 2x bf16 (RTNE)
__device__ __forceinline__ int pk_bf16(float lo, float hi) {
    unsigned int ul = __float_as_uint(lo);
    ul += 0x7fffu + ((ul >> 16) & 1u);
    unsigned int uh = __float_as_uint(hi);
    uh += 0x7fffu + ((uh >> 16) & 1u);
    return (int)((ul >> 16) | (uh & 0xffff0000u));
}

// DPP-based sum over each aligned 16-lane group (4 VALU adds, no DS ops).
template <int CTRL>
__device__ __forceinline__ float dpp_add_(float v) {
    int t = __builtin_amdgcn_update_dpp(
        0, __float_as_int(v), CTRL, 0xF, 0xF, true);
    return v + __int_as_float(t);
}
__device__ __forceinline__ float red16_(float p) {
    p = dpp_add_<0xB1>(p);   // quad_perm(1,0,3,2)  : + lane^1
    p = dpp_add_<0x4E>(p);   // quad_perm(2,3,0,1)  : + lane^2
    p = dpp_add_<0x141>(p);  // row_half_mirror     : + other quad in 8
    p = dpp_add_<0x140>(p);  // row_mirror          : + other 8 in 16
    return p;                // all 16 lanes hold the group sum
}

// XOR-swizzled LDS chunk address: tile is [128 rows][4 chunks of 8 bf16].
__device__ __forceinline__ int swz(int row, int chunk) {
    return (((row << 2) + chunk) ^ (row & 7)) << 3;
}

// ---------------------------------------------------------------------------
// bf16 MFMA GEMM: C[M,N] = A[M,K] @ W[N,K]^T. W fp32 (packed in staging).
// ABF16==0: A fp32, packed in staging. ABF16==1: A already bf16 [M][K].
// 128x128 tile, 4 waves (2x2 of 64x64), BK=32. M%128==0, N%128==0, K%32==0.
// SPLIT==1: cols < DI -> C plain; cols >= DI -> C2 with silu applied.
// Split-K via blockIdx.z: A += z*za (elems), W += z*zw, C += z*zc; pass K=Kc.
// ---------------------------------------------------------------------------
template <int SPLIT, int ABF16>
__global__ __launch_bounds__(256) void gemm_bf16_f32in(
    const void* __restrict__ Av, int lda,
    const float* __restrict__ W, int ldw,
    float* __restrict__ C, float* __restrict__ C2, int ldc, int K,
    int za, int zw, long zc)
{
    __shared__ __align__(16) unsigned short As[128 * 32];
    __shared__ __align__(16) unsigned short Ws[128 * 32];

    const int tid  = threadIdx.x;
    const int lane = tid & 63;
    const int wave = tid >> 6;
    const int bm = blockIdx.y * 128;
    const int bn = blockIdx.x * 128;
    const int z  = blockIdx.z;
    C += (size_t)z * zc;

    const int srow = tid >> 1;
    const int cb   = (tid & 1) * 2;
    const float* Ag = (ABF16 ? nullptr
        : (const float*)Av + (size_t)z * za + (size_t)(bm + srow) * lda + cb * 8);
    const unsigned short* Ag16 = (ABF16
        ? (const unsigned short*)Av + (size_t)z * za
          + (size_t)(bm + srow) * lda + cb * 8 : nullptr);
    const float* Wg = W + (size_t)z * zw + (size_t)(bn + srow) * ldw + cb * 8;
    const int ia0 = swz(srow, cb);
    const int ia1 = swz(srow, cb + 1);

    const int wr = (wave >> 1) * 64;
    const int wc = (wave & 1) * 64;
    const int fr = lane & 15;
    const int fq = lane >> 4;

    f32x4 acc[4][4];
#pragma unroll
    for (int m = 0; m < 4; ++m)
#pragma unroll
        for (int n = 0; n < 4; ++n) acc[m][n] = (f32x4){0.f, 0.f, 0.f, 0.f};

    for (int k0 = 0; k0 < K; k0 += 32) {
        int4 pa0, pa1;
        if (ABF16) {
            pa0 = *(const int4*)(Ag16 + k0);
            pa1 = *(const int4*)(Ag16 + k0 + 8);
        } else {
            const float4 a0 = *(const float4*)(Ag + k0);
            const float4 a1 = *(const float4*)(Ag + k0 + 4);
            const float4 a2 = *(const float4*)(Ag + k0 + 8);
            const float4 a3 = *(const float4*)(Ag + k0 + 12);
            pa0 = (int4){pk_bf16(a0.x, a0.y), pk_bf16(a0.z, a0.w),
                         pk_bf16(a1.x, a1.y), pk_bf16(a1.z, a1.w)};
            pa1 = (int4){pk_bf16(a2.x, a2.y), pk_bf16(a2.z, a2.w),
                         pk_bf16(a3.x, a3.y), pk_bf16(a3.z, a3.w)};
        }
        const float4 w0 = *(const float4*)(Wg + k0);
        const float4 w1 = *(const float4*)(Wg + k0 + 4);
        const float4 w2 = *(const float4*)(Wg + k0 + 8);
        const float4 w3 = *(const float4*)(Wg + k0 + 12);

        __syncthreads();
        {
            const int4 pw0 = {pk_bf16(w0.x, w0.y), pk_bf16(w0.z, w0.w),
                              pk_bf16(w1.x, w1.y), pk_bf16(w1.z, w1.w)};
            const int4 pw1 = {pk_bf16(w2.x, w2.y), pk_bf16(w2.z, w2.w),
                              pk_bf16(w3.x, w3.y), pk_bf16(w3.z, w3.w)};
            *(int4*)(As + ia0) = pa0;
            *(int4*)(As + ia1) = pa1;
            *(int4*)(Ws + ia0) = pw0;
            *(int4*)(Ws + ia1) = pw1;
        }
        __syncthreads();

        bf16x8 af[4], bfv[4];
#pragma unroll
        for (int m = 0; m < 4; ++m)
            af[m] = *(const bf16x8*)(As + swz(wr + m * 16 + fr, fq));
#pragma unroll
        for (int n = 0; n < 4; ++n)
            bfv[n] = *(const bf16x8*)(Ws + swz(wc + n * 16 + fr, fq));
#pragma unroll
        for (int m = 0; m < 4; ++m)
#pragma unroll
            for (int n = 0; n < 4; ++n)
                acc[m][n] = __builtin_amdgcn_mfma_f32_16x16x32_bf16(
                    af[m], bfv[n], acc[m][n], 0, 0, 0);
    }

#pragma unroll
    for (int m = 0; m < 4; ++m)
#pragma unroll
        for (int n = 0; n < 4; ++n) {
            const int col = bn + wc + n * 16 + fr;
#pragma unroll
            for (int j = 0; j < 4; ++j) {
                const int row = bm + wr + m * 16 + fq * 4 + j;
                const float v = acc[m][n][j];
                if (SPLIT) {
                    if (col < DI) {
                        C[(size_t)row * ldc + col] = v;
                    } else {
                        C2[(size_t)row * ldc + (col - DI)] = v * sigmoidf_(v);
                    }
                } else {
                    C[(size_t)row * ldc + col] = v;
                }
            }
        }
}

// ---------------------------------------------------------------------------
// reduce 4 split-K partials -> out (float4 vectorized)
// ---------------------------------------------------------------------------
__global__ __launch_bounds__(256) void reduce4_kernel(
    const float* __restrict__ part, float* __restrict__ out, int n4)
{
    const int i = blockIdx.x * 256 + threadIdx.x;
    if (i >= n4) return;
    const size_t stride = (size_t)ML * DM;
    float4 a = *(const float4*)(part + (size_t)i * 4);
    const float4 b = *(const float4*)(part + stride + (size_t)i * 4);
    const float4 c = *(const float4*)(part + 2 * stride + (size_t)i * 4);
    const float4 d = *(const float4*)(part + 3 * stride + (size_t)i * 4);
    a.x += b.x + c.x + d.x;
    a.y += b.y + c.y + d.y;
    a.z += b.z + c.z + d.z;
    a.w += b.w + c.w + d.w;
    *(float4*)(out + (size_t)i * 4) = a;
}

// ---------------------------------------------------------------------------
// Generic fp32 GEMM: C[M,N] = A[M,K] @ W[N,K]^T.
// ATRANS==1: A is stored transposed [K][M].
// Split-K via blockIdx.z: A += z*za, W += z*zw, C += z*zc.
// EPI==2: C = softplus(C + bias[row]).
// ---------------------------------------------------------------------------
template <int EPI, int ATRANS>
__global__ __launch_bounds__(256) void gemm_nt(
    const float* __restrict__ A, int lda,
    const float* __restrict__ W, int ldw,
    float* __restrict__ C, int ldc,
    int N, int K, const float* __restrict__ bias, int za, int zw, int zc)
{
    A += (size_t)blockIdx.z * za;
    W += (size_t)blockIdx.z * zw;
    C += (size_t)blockIdx.z * zc;

    __shared__ float Asl[16][132];
    __shared__ float Wsl[16][132];

    const int tid = threadIdx.x;
    const int tx = tid & 15;
    const int ty = tid >> 4;
    const int bm = blockIdx.y * 128;
    const int bn = blockIdx.x * 128;

    const int lr = tid >> 1;
    const int lk = (tid & 1) * 8;
    const int krow = tid >> 4;          // ATRANS staging map
    const int mseg = (tid & 15) * 8;

    float acc[8][8];
#pragma unroll
    for (int i = 0; i < 8; ++i)
#pragma unroll
        for (int j = 0; j < 8; ++j) acc[i][j] = 0.0f;

    const float* Ap = ATRANS
        ? A + (size_t)krow * lda + bm + mseg
        : A + (size_t)(bm + lr) * lda + lk;
    const float* Wp = W + (size_t)(bn + lr) * ldw + lk;
    const bool wok = (bn + lr) < N;
    const float4 f4z = make_float4(0.f, 0.f, 0.f, 0.f);

    for (int k0 = 0; k0 < K; k0 += 16) {
        float4 av0, av1;
        if (ATRANS) {
            av0 = *(const float4*)(Ap + (size_t)k0 * lda);
            av1 = *(const float4*)(Ap + (size_t)k0 * lda + 4);
        } else {
            av0 = *(const float4*)(Ap + k0);
            av1 = *(const float4*)(Ap + k0 + 4);
        }
        const float4 wv0 = wok ? *(const float4*)(Wp + k0)     : f4z;
        const float4 wv1 = wok ? *(const float4*)(Wp + k0 + 4) : f4z;

        __syncthreads();
        if (ATRANS) {
            *(float4*)&Asl[krow][mseg]     = av0;
            *(float4*)&Asl[krow][mseg + 4] = av1;
        } else {
            Asl[lk + 0][lr] = av0.x; Asl[lk + 1][lr] = av0.y;
            Asl[lk + 2][lr] = av0.z; Asl[lk + 3][lr] = av0.w;
            Asl[lk + 4][lr] = av1.x; Asl[lk + 5][lr] = av1.y;
            Asl[lk + 6][lr] = av1.z; Asl[lk + 7][lr] = av1.w;
        }
        Wsl[lk + 0][lr] = wv0.x; Wsl[lk + 1][lr] = wv0.y;
        Wsl[lk + 2][lr] = wv0.z; Wsl[lk + 3][lr] = wv0.w;
        Wsl[lk + 4][lr] = wv1.x; Wsl[lk + 5][lr] = wv1.y;
        Wsl[lk + 6][lr] = wv1.z; Wsl[lk + 7][lr] = wv1.w;
        __syncthreads();

#pragma unroll
        for (int k = 0; k < 16; ++k) {
            const float4 a0 = *(const float4*)&Asl[k][(ty << 2)];
            const float4 a1 = *(const float4*)&Asl[k][64 + (ty << 2)];
            const float4 b0 = *(const float4*)&Wsl[k][(tx << 2)];
            const float4 b1 = *(const float4*)&Wsl[k][64 + (tx << 2)];
            const float ar[8] = {a0.x, a0.y, a0.z, a0.w, a1.x, a1.y, a1.z, a1.w};
            const float br[8] = {b0.x, b0.y, b0.z, b0.w, b1.x, b1.y, b1.z, b1.w};
#pragma unroll
            for (int i = 0; i < 8; ++i)
#pragma unroll
                for (int j = 0; j < 8; ++j)
                    acc[i][j] = fmaf(ar[i], br[j], acc[i][j]);
        }
    }

#pragma unroll
    for (int i = 0; i < 8; ++i) {
        const int row = bm + ((i & 4) << 4) + (ty << 2) + (i & 3);
#pragma unroll
        for (int j = 0; j < 8; ++j) {
            const int col = bn + ((j & 4) << 4) + (tx << 2) + (j & 3);
            if (col < N) {
                float v = acc[i][j];
                if (EPI == 2) {
                    v += bias[row];
                    v = (v > 20.f) ? v : log1pf(__expf(v));
                }
                C[(size_t)row * ldc + col] = v;
            }
        }
    }
}

// ---------------------------------------------------------------------------
// Reduce split-K partials: xdbl[m][j] = sum_kc part[m*768 + kc*96 + j].
// Also scatter-writes the transposed B/C block: bcT[j-64][m] for j>=64.
// ---------------------------------------------------------------------------
__global__ __launch_bounds__(256) void reduce_xdbl_kernel(
    const float* __restrict__ part, float* __restrict__ xdbl,
    float* __restrict__ bcT)
{
    const int idx = blockIdx.x * 256 + threadIdx.x;
    if (idx >= ML * DXD) return;
    const int m = idx / DXD;
    const int j = idx - m * DXD;
    const float* p = part + (size_t)m * 768 + j;
    float s = 0.0f;
#pragma unroll
    for (int kc = 0; kc < 8; ++kc) s += p[kc * DXD];
    xdbl[idx] = s;
    if (j >= DTR) bcT[(size_t)(j - DTR) * ML + m] = s;
}

// ---------------------------------------------------------------------------
// Depthwise causal conv (width 4) + bias + SiLU, TRANSPOSING output:
// reads xc[m][d] tiles (coalesced, +3 halo rows), writes xT[d][m] (coalesced).
// Block: 32 d x 256 m.
// ---------------------------------------------------------------------------
constexpr int CT_LDS = 260;   // LDS row stride (words)
__global__ __launch_bounds__(256) void conv_transpose_kernel(
    const float* __restrict__ xc,
    const float* __restrict__ conv_w,
    const float* __restrict__ conv_b,
    float* __restrict__ xT)
{
    __shared__ float tile[32][CT_LDS];
    const int d0 = blockIdx.x * 32;
    const int m0 = blockIdx.y * 256;
    const int t  = threadIdx.x;
    const bool atStart = ((m0 & (Ls - 1)) == 0);

    // load rows r=-3..255  ->  tile[d][3+r]
    for (int rg = 0; rg < 33; ++rg) {
        const int r = rg * 8 + (t >> 5) - 3;
        const int dcol = t & 31;
        if (r <= 255) {
            float v = 0.0f;
            if (r >= 0 || !atStart)
                v = xc[(size_t)(m0 + r) * DI + d0 + dcol];
            tile[dcol][3 + r] = v;
        }
    }
    __syncthreads();

    const int dd  = t >> 3;
    const int seg = (t & 7) * 32;
    const int d   = d0 + dd;
    const float4 cw = *(const float4*)(conv_w + (d << 2));
    const float  cb = conv_b[d];
    float* dst = xT + (size_t)d * ML + m0 + seg;

    float4 cur = *(const float4*)&tile[dd][seg];
#pragma unroll
    for (int g = 0; g < 8; ++g) {
        const float4 nxt = *(const float4*)&tile[dd][seg + 4 * g + 4];
        const float a0 = cb + cw.x*cur.x + cw.y*cur.y + cw.z*cur.z + cw.w*cur.w;
        const float a1 = cb + cw.x*cur.y + cw.y*cur.z + cw.z*cur.w + cw.w*nxt.x;
        const float a2 = cb + cw.x*cur.z + cw.y*cur.w + cw.z*nxt.x + cw.w*nxt.y;
        const float a3 = cb + cw.x*cur.w + cw.y*nxt.x + cw.z*nxt.y + cw.w*nxt.z;
        float4 o;
        o.x = a0 * sigmoidf_(a0); o.y = a1 * sigmoidf_(a1);
        o.z = a2 * sigmoidf_(a2); o.w = a3 * sigmoidf_(a3);
        *(float4*)(dst + 4 * g) = o;
        cur = nxt;
    }
}

// ---------------------------------------------------------------------------
// Chunked scan pass 1 (chunks 0..NCH-2): per (b,c,d,n) run CHL steps from
// h=0; emit chunk-end state hend and chunk decay exp(Anat * sum(dt)).
// ---------------------------------------------------------------------------
__global__ __launch_bounds__(256) void scan_pass1(
    const float* __restrict__ dtT,     // [DI][ML]
    const float* __restrict__ xT,      // [DI][ML]
    const float* __restrict__ bcT,     // [32][ML]
    const float* __restrict__ A_log,
    float* __restrict__ hend, float* __restrict__ Dprod)
{
    const int b    = blockIdx.z;
    const int c    = blockIdx.y;
    const int lane = threadIdx.x & 63;
    const int wave = threadIdx.x >> 6;
    const int n    = lane & 15;
    const int dl   = lane >> 4;
    const int d    = blockIdx.x * 16 + wave * 4 + dl;
    const int m0   = b * Ls + c * CHL;

    const float Anat = -__expf(A_log[(d << 4) + n]);

    const float4* dtp = (const float4*)(dtT + (size_t)d * ML + m0);
    const float4* xp  = (const float4*)(xT  + (size_t)d * ML + m0);
    const float4* Bp  = (const float4*)(bcT + (size_t)n * ML + m0);

    float4 dt4 = dtp[0], x4 = xp[0], B4 = Bp[0];
    float h = 0.0f, S = 0.0f;

    for (int it = 0; it < CHL / 4; ++it) {
        const float4 dtc = dt4, xc4 = x4, Bc = B4;
        if (it + 1 < CHL / 4) {
            dt4 = dtp[it + 1]; x4 = xp[it + 1]; B4 = Bp[it + 1];
        }
#pragma unroll
        for (int i = 0; i < 4; ++i) {
            const float dtv = ((const float*)&dtc)[i];
            const float xv  = ((const float*)&xc4)[i];
            const float Bn  = ((const float*)&Bc)[i];
            S += dtv;
            const float e = __expf(dtv * Anat);
            h = fmaf(e, h, dtv * xv * Bn);
        }
    }

    const size_t idx = (((size_t)(b * NCH + c) * DI + d) << 4) + n;
    hend[idx]  = h;
    Dprod[idx] = __expf(Anat * S);
}

// ---------------------------------------------------------------------------
// Chunked scan pass 2: fold h_init inline, run CHL steps, DPP-reduce y over
// n, add x*D. Writes ungated yT IN-PLACE over xT (block owns its cells).
// ---------------------------------------------------------------------------
__global__ __launch_bounds__(256) void scan_pass2(
    const float* __restrict__ dtT,     // [DI][ML]
    float* xT,                          // in: x, out: yT (in-place)
    const float* __restrict__ bcT,     // [32][ML]
    const float* __restrict__ A_log,
    const float* __restrict__ Dp,
    const float* __restrict__ hend, const float* __restrict__ Dprod)
{
    const int b    = blockIdx.z;
    const int c    = blockIdx.y;
    const int lane = threadIdx.x & 63;
    const int wave = threadIdx.x >> 6;
    const int n    = lane & 15;
    const int dl   = lane >> 4;
    const int d    = blockIdx.x * 16 + wave * 4 + dl;
    const int m0   = b * Ls + c * CHL;

    const float Anat = -__expf(A_log[(d << 4) + n]);
    const float dpd  = Dp[d];

    // fold chunk summaries 0..c-1 -> h_init
    float h = 0.0f;
    for (int cp = 0; cp < c; ++cp) {
        const size_t off = (((size_t)(b * NCH + cp) * DI + d) << 4) + n;
        h = fmaf(Dprod[off], h, hend[off]);
    }

    const float4* dtp = (const float4*)(dtT + (size_t)d * ML + m0);
    const float4* xp  = (const float4*)(xT  + (size_t)d * ML + m0);
    const float4* Bp  = (const float4*)(bcT + (size_t)n * ML + m0);
    const float4* Cp  = (const float4*)(bcT + (size_t)(DST + n) * ML + m0);
    float4* yq = (float4*)(xT + (size_t)d * ML + m0);

    float4 dt4 = dtp[0], x4 = xp[0], B4 = Bp[0], C4 = Cp[0];

    for (int it = 0; it < CHL / 4; ++it) {
        const float4 dtc = dt4, xc4 = x4, Bc = B4, Cc = C4;
        if (it + 1 < CHL / 4) {
            dt4 = dtp[it + 1]; x4 = xp[it + 1];
            B4 = Bp[it + 1];   C4 = Cp[it + 1];
        }
        float4 y4;
#pragma unroll
        for (int i = 0; i < 4; ++i) {
            const float dtv = ((const float*)&dtc)[i];
            const float xv  = ((const float*)&xc4)[i];
            const float Bn  = ((const float*)&Bc)[i];
            const float Cn  = ((const float*)&Cc)[i];
            const float e = __expf(dtv * Anat);
            h = fmaf(e, h, dtv * xv * Bn);
            const float p = red16_(h * Cn);
            ((float*)&y4)[i] = fmaf(xv, dpd, p);
        }
        if (n == 0) yq[it] = y4;
    }
}

// ---------------------------------------------------------------------------
// Gate + transpose: y_bf16[m][d] = bf16( yT[d][m] * zg[m][d] ).
// ---------------------------------------------------------------------------
__global__ __launch_bounds__(256) void gate_transpose_kernel(
    const float* __restrict__ yT,       // [DI][ML]
    const float* __restrict__ zg,       // [ML][DI]  (silu already applied)
    unsigned short* __restrict__ yb)    // [ML][DI] bf16
{
    __shared__ float Ty[64][65];
    __shared__ float Tz[64][65];
    const int d0 = blockIdx.x * 64;
    const int m0 = blockIdx.y * 64;
    const int t  = threadIdx.x;
    const int cc = t & 63, r4 = t >> 6;

#pragma unroll 4
    for (int rr = 0; rr < 16; ++rr) {
        const int r = rr * 4 + r4;
        Ty[r][cc] = yT[(size_t)(d0 + r) * ML + m0 + cc];
        Tz[r][cc] = zg[(size_t)(m0 + r) * DI + d0 + cc];
    }
    __syncthreads();

    const int dp  = (t & 31) * 2;
    const int mr4 = t >> 5;
#pragma unroll 4
    for (int rr = 0; rr < 8; ++rr) {
        const int mr = rr * 8 + mr4;
        const float v0 = Ty[dp][mr]     * Tz[mr][dp];
        const float v1 = Ty[dp + 1][mr] * Tz[mr][dp + 1];
        *(unsigned int*)(yb + (size_t)(m0 + mr) * DI + d0 + dp) =
            (unsigned int)pk_bf16(v0, v1);
    }
}

// ---------------------------------------------------------------------------
extern "C" void kernel_launch(void* const* d_in, const int* in_sizes, int n_in,
                              void* d_out, int out_size, void* d_ws, size_t ws_size,
                              hipStream_t stream)
{
    const float* x      = (const float*)d_in[0];
    const float* W_in   = (const float*)d_in[1];
    const float* conv_w = (const float*)d_in[2];
    const float* conv_b = (const float*)d_in[3];
    const float* W_x    = (const float*)d_in[4];
    const float* W_dt   = (const float*)d_in[5];
    const float* b_dt   = (const float*)d_in[6];
    const float* A_log  = (const float*)d_in[7];
    const float* Dp     = (const float*)d_in[8];
    const float* W_out  = (const float*)d_in[9];
    float* out = (float*)d_out;

    // workspace (proven 48.75 MB footprint):
    float* ws     = (float*)d_ws;
    float* xc_arr = ws;                         // 16 MB: xc -> splitK partials -> dtT -> y_bf16
    float* zg_arr = xc_arr + (size_t)ML * DI;   // 16 MB: silu(z) [m][d]; later outGEMM partials 0-1
    float* xT_arr = zg_arr + (size_t)ML * DI;   // 16 MB: xT[d][m] -> yT; later outGEMM partials 2-3
    float* xdbl   = xT_arr + (size_t)ML * DI;   // 0.75 MB

    // d_out scratch (dead until gate/out-GEMM): 4.25 MB of 8 MB
    float* hend  = out;                                   // 2 MB
    float* Dprod = hend + (size_t)Bb * NCH * DI * DST;    // 2 MB
    float* bcT   = Dprod + (size_t)Bb * NCH * DI * DST;   // [32][2048] 0.25 MB

    float* dtT = xc_arr;                                  // [DI][ML] over xc
    unsigned short* ybf = (unsigned short*)xc_arr;        // bf16 y[m][d], 8 MB
    float* oPart = zg_arr;   // out-GEMM split-K partials: 4 x 8 MB (zg+xT dead)

    const dim3 blk(256);

    // 1) in-proj: xc | silu(z) = x @ W_in^T   (bf16 MFMA, split epilogue)
    gemm_bf16_f32in<1, 0><<<dim3(DXZ / 128, ML / 128), blk, 0, stream>>>(
        x, DM, W_in, DM, xc_arr, zg_arr, DI, DM, 0, 0, 0);

    // 2) depthwise causal conv + silu, transposed -> xT[d][m]
    conv_transpose_kernel<<<dim3(DI / 32, ML / 256), blk, 0, stream>>>(
        xc_arr, conv_w, conv_b, xT_arr);

    // 3) x_dbl partials = x @ W_x^T from xT (ATRANS, split-K x8) -> xc (dead)
    gemm_nt<0, 1><<<dim3(1, ML / 128, 8), blk, 0, stream>>>(
        xT_arr, ML, W_x, DI, xc_arr, 768, DXD, DI / 8, nullptr,
        (DI / 8) * ML, DI / 8, DXD);
    reduce_xdbl_kernel<<<dim3((ML * DXD + 255) / 256), blk, 0, stream>>>(
        xc_arr, xdbl, bcT);

    // 4) dt_T = softplus(W_dt @ x_dbl[:, :64]^T + b_dt[row])  [DI][ML] over xc
    gemm_nt<2, 0><<<dim3(ML / 128, DI / 128), blk, 0, stream>>>(
        W_dt, DTR, xdbl, DXD, dtT, ML, ML, DTR, b_dt, 0, 0, 0);

    // 5) chunked selective scan; pass2 writes ungated yT in-place over xT
    scan_pass1<<<dim3(DI / 16, NCH - 1, Bb), blk, 0, stream>>>(
        dtT, xT_arr, bcT, A_log, hend, Dprod);
    scan_pass2<<<dim3(DI / 16, NCH, Bb), blk, 0, stream>>>(
        dtT, xT_arr, bcT, A_log, Dp, hend, Dprod);

    // 6) gate + transpose: y_bf16[m][d] = yT * silu(z)   (dtT now dead)
    gate_transpose_kernel<<<dim3(DI / 64, ML / 64), blk, 0, stream>>>(
        xT_arr, zg_arr, ybf);

    // 7) out partials = y_bf16 @ W_out^T  (bf16-A MFMA, split-K x4)
    //    zg/xT now dead -> 4 x 8 MB partials at oPart
    gemm_bf16_f32in<0, 1><<<dim3(DM / 128, ML / 128, 4), blk, 0, stream>>>(
        ybf, DI, W_out, DI, oPart, nullptr, DM, DI / 4,
        DI / 4, DI / 4, (long)ML * DM);

    // 8) out = sum of 4 partials
    reduce4_kernel<<<dim3((ML * DM / 4 + 255) / 256), blk, 0, stream>>>(
        oPart, out, ML * DM / 4);
}

// Round 11
// 409.236 us; speedup vs baseline: 1.2299x; 1.0051x over previous
//
#include <hip/hip_runtime.h>
#include <hip/hip_bf16.h>
#include <math.h>

// Problem constants (B=2, L=1024, d_model=1024, d_inner=2048)
constexpr int Bb  = 2;
constexpr int Ls  = 1024;
constexpr int DM  = 1024;   // d_model
constexpr int DI  = 2048;   // d_inner
constexpr int DXZ = 4096;   // 2*d_inner
constexpr int DXD = 96;     // dt_rank + 2*d_state
constexpr int DTR = 64;     // dt_rank
constexpr int DST = 16;     // d_state
constexpr int NCH = 16;     // scan chunks
constexpr int CHL = 64;     // chunk length (NCH*CHL == Ls)
constexpr int ML  = Bb * Ls;   // 2048 rows total

typedef __attribute__((ext_vector_type(8))) short bf16x8;
typedef __attribute__((ext_vector_type(4))) float f32x4;

__device__ __forceinline__ float sigmoidf_(float v) {
    return 1.0f / (1.0f + __expf(-v));
}

// pack two fp32 -> one dword of 2x bf16 (RTNE)
__device__ __forceinline__ int pk_bf16(float lo, float hi) {
    unsigned int ul = __float_as_uint(lo);
    ul += 0x7fffu + ((ul >> 16) & 1u);
    unsigned int uh = __float_as_uint(hi);
    uh += 0x7fffu + ((uh >> 16) & 1u);
    return (int)((ul >> 16) | (uh & 0xffff0000u));
}

// DPP-based sum over each aligned 16-lane group (4 VALU adds, no DS ops).
template <int CTRL>
__device__ __forceinline__ float dpp_add_(float v) {
    int t = __builtin_amdgcn_update_dpp(
        0, __float_as_int(v), CTRL, 0xF, 0xF, true);
    return v + __int_as_float(t);
}
__device__ __forceinline__ float red16_(float p) {
    p = dpp_add_<0xB1>(p);   // quad_perm(1,0,3,2)  : + lane^1
    p = dpp_add_<0x4E>(p);   // quad_perm(2,3,0,1)  : + lane^2
    p = dpp_add_<0x141>(p);  // row_half_mirror     : + other quad in 8
    p = dpp_add_<0x140>(p);  // row_mirror          : + other 8 in 16
    return p;                // all 16 lanes hold the group sum
}

// XOR-swizzled LDS chunk address: tile is [128 rows][4 chunks of 8 bf16].
__device__ __forceinline__ int swz(int row, int chunk) {
    return (((row << 2) + chunk) ^ (row & 7)) << 3;
}

// ---------------------------------------------------------------------------
// fp32 -> bf16 elementwise convert (4 elems/thread)
// ---------------------------------------------------------------------------
__global__ __launch_bounds__(256) void cvt_bf16_kernel(
    const float* __restrict__ in, unsigned short* __restrict__ out, int n4)
{
    const int i = blockIdx.x * 256 + threadIdx.x;
    if (i >= n4) return;
    const float4 v = *(const float4*)(in + (size_t)i * 4);
    *(int2*)(out + (size_t)i * 4) =
        make_int2(pk_bf16(v.x, v.y), pk_bf16(v.z, v.w));
}

// ---------------------------------------------------------------------------
// bf16 MFMA GEMM: C[M,N] = A[M,K] @ W[N,K]^T.
// ABF16/WBF16: operand already bf16 [rows][K]; else fp32, packed in staging.
// 128x128 tile, 4 waves (2x2 of 64x64), BK=32. M%128==0, N%128==0, K%32==0.
// SPLIT==1: cols < DI -> C plain; cols >= DI -> C2 with silu applied.
// Split-K via blockIdx.z: A += z*za (elems), W += z*zw, C += z*zc; pass K=Kc.
// ---------------------------------------------------------------------------
template <int SPLIT, int ABF16, int WBF16>
__global__ __launch_bounds__(256) void gemm_bf16_f32in(
    const void* __restrict__ Av, int lda,
    const void* __restrict__ Wv, int ldw,
    float* __restrict__ C, float* __restrict__ C2, int ldc, int K,
    int za, int zw, long zc)
{
    __shared__ __align__(16) unsigned short As[128 * 32];
    __shared__ __align__(16) unsigned short Ws[128 * 32];

    const int tid  = threadIdx.x;
    const int lane = tid & 63;
    const int wave = tid >> 6;
    const int bm = blockIdx.y * 128;
    const int bn = blockIdx.x * 128;
    const int z  = blockIdx.z;
    C += (size_t)z * zc;

    const int srow = tid >> 1;
    const int cb   = (tid & 1) * 2;
    const float* Ag = (ABF16 ? nullptr
        : (const float*)Av + (size_t)z * za + (size_t)(bm + srow) * lda + cb * 8);
    const unsigned short* Ag16 = (ABF16
        ? (const unsigned short*)Av + (size_t)z * za
          + (size_t)(bm + srow) * lda + cb * 8 : nullptr);
    const float* Wg = (WBF16 ? nullptr
        : (const float*)Wv + (size_t)z * zw + (size_t)(bn + srow) * ldw + cb * 8);
    const unsigned short* Wg16 = (WBF16
        ? (const unsigned short*)Wv + (size_t)z * zw
          + (size_t)(bn + srow) * ldw + cb * 8 : nullptr);
    const int ia0 = swz(srow, cb);
    const int ia1 = swz(srow, cb + 1);

    const int wr = (wave >> 1) * 64;
    const int wc = (wave & 1) * 64;
    const int fr = lane & 15;
    const int fq = lane >> 4;

    f32x4 acc[4][4];
#pragma unroll
    for (int m = 0; m < 4; ++m)
#pragma unroll
        for (int n = 0; n < 4; ++n) acc[m][n] = (f32x4){0.f, 0.f, 0.f, 0.f};

    for (int k0 = 0; k0 < K; k0 += 32) {
        int4 pa0, pa1, pw0, pw1;
        if (ABF16) {
            pa0 = *(const int4*)(Ag16 + k0);
            pa1 = *(const int4*)(Ag16 + k0 + 8);
        } else {
            const float4 a0 = *(const float4*)(Ag + k0);
            const float4 a1 = *(const float4*)(Ag + k0 + 4);
            const float4 a2 = *(const float4*)(Ag + k0 + 8);
            const float4 a3 = *(const float4*)(Ag + k0 + 12);
            pa0 = (int4){pk_bf16(a0.x, a0.y), pk_bf16(a0.z, a0.w),
                         pk_bf16(a1.x, a1.y), pk_bf16(a1.z, a1.w)};
            pa1 = (int4){pk_bf16(a2.x, a2.y), pk_bf16(a2.z, a2.w),
                         pk_bf16(a3.x, a3.y), pk_bf16(a3.z, a3.w)};
        }
        if (WBF16) {
            pw0 = *(const int4*)(Wg16 + k0);
            pw1 = *(const int4*)(Wg16 + k0 + 8);
        } else {
            const float4 w0 = *(const float4*)(Wg + k0);
            const float4 w1 = *(const float4*)(Wg + k0 + 4);
            const float4 w2 = *(const float4*)(Wg + k0 + 8);
            const float4 w3 = *(const float4*)(Wg + k0 + 12);
            pw0 = (int4){pk_bf16(w0.x, w0.y), pk_bf16(w0.z, w0.w),
                         pk_bf16(w1.x, w1.y), pk_bf16(w1.z, w1.w)};
            pw1 = (int4){pk_bf16(w2.x, w2.y), pk_bf16(w2.z, w2.w),
                         pk_bf16(w3.x, w3.y), pk_bf16(w3.z, w3.w)};
        }

        __syncthreads();
        *(int4*)(As + ia0) = pa0;
        *(int4*)(As + ia1) = pa1;
        *(int4*)(Ws + ia0) = pw0;
        *(int4*)(Ws + ia1) = pw1;
        __syncthreads();

        bf16x8 af[4], bfv[4];
#pragma unroll
        for (int m = 0; m < 4; ++m)
            af[m] = *(const bf16x8*)(As + swz(wr + m * 16 + fr, fq));
#pragma unroll
        for (int n = 0; n < 4; ++n)
            bfv[n] = *(const bf16x8*)(Ws + swz(wc + n * 16 + fr, fq));
#pragma unroll
        for (int m = 0; m < 4; ++m)
#pragma unroll
            for (int n = 0; n < 4; ++n)
                acc[m][n] = __builtin_amdgcn_mfma_f32_16x16x32_bf16(
                    af[m], bfv[n], acc[m][n], 0, 0, 0);
    }

#pragma unroll
    for (int m = 0; m < 4; ++m)
#pragma unroll
        for (int n = 0; n < 4; ++n) {
            const int col = bn + wc + n * 16 + fr;
#pragma unroll
            for (int j = 0; j < 4; ++j) {
                const int row = bm + wr + m * 16 + fq * 4 + j;
                const float v = acc[m][n][j];
                if (SPLIT) {
                    if (col < DI) {
                        C[(size_t)row * ldc + col] = v;
                    } else {
                        C2[(size_t)row * ldc + (col - DI)] = v * sigmoidf_(v);
                    }
                } else {
                    C[(size_t)row * ldc + col] = v;
                }
            }
        }
}

// ---------------------------------------------------------------------------
// reduce 4 split-K partials -> out (float4 vectorized)
// ---------------------------------------------------------------------------
__global__ __launch_bounds__(256) void reduce4_kernel(
    const float* __restrict__ part, float* __restrict__ out, int n4)
{
    const int i = blockIdx.x * 256 + threadIdx.x;
    if (i >= n4) return;
    const size_t stride = (size_t)ML * DM;
    float4 a = *(const float4*)(part + (size_t)i * 4);
    const float4 b = *(const float4*)(part + stride + (size_t)i * 4);
    const float4 c = *(const float4*)(part + 2 * stride + (size_t)i * 4);
    const float4 d = *(const float4*)(part + 3 * stride + (size_t)i * 4);
    a.x += b.x + c.x + d.x;
    a.y += b.y + c.y + d.y;
    a.z += b.z + c.z + d.z;
    a.w += b.w + c.w + d.w;
    *(float4*)(out + (size_t)i * 4) = a;
}

// ---------------------------------------------------------------------------
// Generic fp32 GEMM: C[M,N] = A[M,K] @ W[N,K]^T.
// ATRANS==1: A is stored transposed [K][M].
// Split-K via blockIdx.z: A += z*za, W += z*zw, C += z*zc.
// EPI==2: C = softplus(C + bias[row]).
// ---------------------------------------------------------------------------
template <int EPI, int ATRANS>
__global__ __launch_bounds__(256) void gemm_nt(
    const float* __restrict__ A, int lda,
    const float* __restrict__ W, int ldw,
    float* __restrict__ C, int ldc,
    int N, int K, const float* __restrict__ bias, int za, int zw, int zc)
{
    A += (size_t)blockIdx.z * za;
    W += (size_t)blockIdx.z * zw;
    C += (size_t)blockIdx.z * zc;

    __shared__ float Asl[16][132];
    __shared__ float Wsl[16][132];

    const int tid = threadIdx.x;
    const int tx = tid & 15;
    const int ty = tid >> 4;
    const int bm = blockIdx.y * 128;
    const int bn = blockIdx.x * 128;

    const int lr = tid >> 1;
    const int lk = (tid & 1) * 8;
    const int krow = tid >> 4;          // ATRANS staging map
    const int mseg = (tid & 15) * 8;

    float acc[8][8];
#pragma unroll
    for (int i = 0; i < 8; ++i)
#pragma unroll
        for (int j = 0; j < 8; ++j) acc[i][j] = 0.0f;

    const float* Ap = ATRANS
        ? A + (size_t)krow * lda + bm + mseg
        : A + (size_t)(bm + lr) * lda + lk;
    const float* Wp = W + (size_t)(bn + lr) * ldw + lk;
    const bool wok = (bn + lr) < N;
    const float4 f4z = make_float4(0.f, 0.f, 0.f, 0.f);

    for (int k0 = 0; k0 < K; k0 += 16) {
        float4 av0, av1;
        if (ATRANS) {
            av0 = *(const float4*)(Ap + (size_t)k0 * lda);
            av1 = *(const float4*)(Ap + (size_t)k0 * lda + 4);
        } else {
            av0 = *(const float4*)(Ap + k0);
            av1 = *(const float4*)(Ap + k0 + 4);
        }
        const float4 wv0 = wok ? *(const float4*)(Wp + k0)     : f4z;
        const float4 wv1 = wok ? *(const float4*)(Wp + k0 + 4) : f4z;

        __syncthreads();
        if (ATRANS) {
            *(float4*)&Asl[krow][mseg]     = av0;
            *(float4*)&Asl[krow][mseg + 4] = av1;
        } else {
            Asl[lk + 0][lr] = av0.x; Asl[lk + 1][lr] = av0.y;
            Asl[lk + 2][lr] = av0.z; Asl[lk + 3][lr] = av0.w;
            Asl[lk + 4][lr] = av1.x; Asl[lk + 5][lr] = av1.y;
            Asl[lk + 6][lr] = av1.z; Asl[lk + 7][lr] = av1.w;
        }
        Wsl[lk + 0][lr] = wv0.x; Wsl[lk + 1][lr] = wv0.y;
        Wsl[lk + 2][lr] = wv0.z; Wsl[lk + 3][lr] = wv0.w;
        Wsl[lk + 4][lr] = wv1.x; Wsl[lk + 5][lr] = wv1.y;
        Wsl[lk + 6][lr] = wv1.z; Wsl[lk + 7][lr] = wv1.w;
        __syncthreads();

#pragma unroll
        for (int k = 0; k < 16; ++k) {
            const float4 a0 = *(const float4*)&Asl[k][(ty << 2)];
            const float4 a1 = *(const float4*)&Asl[k][64 + (ty << 2)];
            const float4 b0 = *(const float4*)&Wsl[k][(tx << 2)];
            const float4 b1 = *(const float4*)&Wsl[k][64 + (tx << 2)];
            const float ar[8] = {a0.x, a0.y, a0.z, a0.w, a1.x, a1.y, a1.z, a1.w};
            const float br[8] = {b0.x, b0.y, b0.z, b0.w, b1.x, b1.y, b1.z, b1.w};
#pragma unroll
            for (int i = 0; i < 8; ++i)
#pragma unroll
                for (int j = 0; j < 8; ++j)
                    acc[i][j] = fmaf(ar[i], br[j], acc[i][j]);
        }
    }

#pragma unroll
    for (int i = 0; i < 8; ++i) {
        const int row = bm + ((i & 4) << 4) + (ty << 2) + (i & 3);
#pragma unroll
        for (int j = 0; j < 8; ++j) {
            const int col = bn + ((j & 4) << 4) + (tx << 2) + (j & 3);
            if (col < N) {
                float v = acc[i][j];
                if (EPI == 2) {
                    v += bias[row];
                    v = (v > 20.f) ? v : log1pf(__expf(v));
                }
                C[(size_t)row * ldc + col] = v;
            }
        }
    }
}

// ---------------------------------------------------------------------------
// Reduce split-K partials of x_dbl:
//   dtlow[m][j] = s        for j < 64   (ld 64)
//   bcT[j-64][m] = s       for j >= 64
// ---------------------------------------------------------------------------
__global__ __launch_bounds__(256) void reduce_xdbl_kernel(
    const float* __restrict__ part, float* __restrict__ dtlow,
    float* __restrict__ bcT)
{
    const int idx = blockIdx.x * 256 + threadIdx.x;
    if (idx >= ML * DXD) return;
    const int m = idx / DXD;
    const int j = idx - m * DXD;
    const float* p = part + (size_t)m * 768 + j;
    float s = 0.0f;
#pragma unroll
    for (int kc = 0; kc < 8; ++kc) s += p[kc * DXD];
    if (j < DTR) dtlow[(size_t)m * DTR + j] = s;
    else         bcT[(size_t)(j - DTR) * ML + m] = s;
}

// ---------------------------------------------------------------------------
// Depthwise causal conv (width 4) + bias + SiLU, TRANSPOSING output:
// reads xc[m][d] tiles (coalesced, +3 halo rows), writes xT[d][m] (coalesced).
// ---------------------------------------------------------------------------
constexpr int CT_LDS = 260;   // LDS row stride (words)
__global__ __launch_bounds__(256) void conv_transpose_kernel(
    const float* __restrict__ xc,
    const float* __restrict__ conv_w,
    const float* __restrict__ conv_b,
    float* __restrict__ xT)
{
    __shared__ float tile[32][CT_LDS];
    const int d0 = blockIdx.x * 32;
    const int m0 = blockIdx.y * 256;
    const int t  = threadIdx.x;
    const bool atStart = ((m0 & (Ls - 1)) == 0);

    // load rows r=-3..255  ->  tile[d][3+r]
    for (int rg = 0; rg < 33; ++rg) {
        const int r = rg * 8 + (t >> 5) - 3;
        const int dcol = t & 31;
        if (r <= 255) {
            float v = 0.0f;
            if (r >= 0 || !atStart)
                v = xc[(size_t)(m0 + r) * DI + d0 + dcol];
            tile[dcol][3 + r] = v;
        }
    }
    __syncthreads();

    const int dd  = t >> 3;
    const int seg = (t & 7) * 32;
    const int d   = d0 + dd;
    const float4 cw = *(const float4*)(conv_w + (d << 2));
    const float  cb = conv_b[d];
    float* dst = xT + (size_t)d * ML + m0 + seg;

    float4 cur = *(const float4*)&tile[dd][seg];
#pragma unroll
    for (int g = 0; g < 8; ++g) {
        const float4 nxt = *(const float4*)&tile[dd][seg + 4 * g + 4];
        const float a0 = cb + cw.x*cur.x + cw.y*cur.y + cw.z*cur.z + cw.w*cur.w;
        const float a1 = cb + cw.x*cur.y + cw.y*cur.z + cw.z*cur.w + cw.w*nxt.x;
        const float a2 = cb + cw.x*cur.z + cw.y*cur.w + cw.z*nxt.x + cw.w*nxt.y;
        const float a3 = cb + cw.x*cur.w + cw.y*nxt.x + cw.z*nxt.y + cw.w*nxt.z;
        float4 o;
        o.x = a0 * sigmoidf_(a0); o.y = a1 * sigmoidf_(a1);
        o.z = a2 * sigmoidf_(a2); o.w = a3 * sigmoidf_(a3);
        *(float4*)(dst + 4 * g) = o;
        cur = nxt;
    }
}

// ---------------------------------------------------------------------------
// Chunked scan pass 1 (chunks 0..NCH-2): per (b,c,d,n) run CHL steps from
// h=0; emit chunk-end state hend and chunk decay exp(Anat * sum(dt)).
// ---------------------------------------------------------------------------
__global__ __launch_bounds__(256) void scan_pass1(
    const float* __restrict__ dtT,     // [DI][ML]
    const float* __restrict__ xT,      // [DI][ML]
    const float* __restrict__ bcT,     // [32][ML]
    const float* __restrict__ A_log,
    float* __restrict__ hend, float* __restrict__ Dprod)
{
    const int b    = blockIdx.z;
    const int c    = blockIdx.y;
    const int lane = threadIdx.x & 63;
    const int wave = threadIdx.x >> 6;
    const int n    = lane & 15;
    const int dl   = lane >> 4;
    const int d    = blockIdx.x * 16 + wave * 4 + dl;
    const int m0   = b * Ls + c * CHL;

    const float Anat = -__expf(A_log[(d << 4) + n]);

    const float4* dtp = (const float4*)(dtT + (size_t)d * ML + m0);
    const float4* xp  = (const float4*)(xT  + (size_t)d * ML + m0);
    const float4* Bp  = (const float4*)(bcT + (size_t)n * ML + m0);

    float4 dt4 = dtp[0], x4 = xp[0], B4 = Bp[0];
    float h = 0.0f, S = 0.0f;

    for (int it = 0; it < CHL / 4; ++it) {
        const float4 dtc = dt4, xc4 = x4, Bc = B4;
        if (it + 1 < CHL / 4) {
            dt4 = dtp[it + 1]; x4 = xp[it + 1]; B4 = Bp[it + 1];
        }
#pragma unroll
        for (int i = 0; i < 4; ++i) {
            const float dtv = ((const float*)&dtc)[i];
            const float xv  = ((const float*)&xc4)[i];
            const float Bn  = ((const float*)&Bc)[i];
            S += dtv;
            const float e = __expf(dtv * Anat);
            h = fmaf(e, h, dtv * xv * Bn);
        }
    }

    const size_t idx = (((size_t)(b * NCH + c) * DI + d) << 4) + n;
    hend[idx]  = h;
    Dprod[idx] = __expf(Anat * S);
}

// ---------------------------------------------------------------------------
// Chunked scan pass 2: fold h_init inline, run CHL steps, DPP-reduce y over
// n, add x*D. Writes ungated yT IN-PLACE over xT (block owns its cells).
// ---------------------------------------------------------------------------
__global__ __launch_bounds__(256) void scan_pass2(
    const float* __restrict__ dtT,     // [DI][ML]
    float* xT,                          // in: x, out: yT (in-place)
    const float* __restrict__ bcT,     // [32][ML]
    const float* __restrict__ A_log,
    const float* __restrict__ Dp,
    const float* __restrict__ hend, const float* __restrict__ Dprod)
{
    const int b    = blockIdx.z;
    const int c    = blockIdx.y;
    const int lane = threadIdx.x & 63;
    const int wave = threadIdx.x >> 6;
    const int n    = lane & 15;
    const int dl   = lane >> 4;
    const int d    = blockIdx.x * 16 + wave * 4 + dl;
    const int m0   = b * Ls + c * CHL;

    const float Anat = -__expf(A_log[(d << 4) + n]);
    const float dpd  = Dp[d];

    // fold chunk summaries 0..c-1 -> h_init
    float h = 0.0f;
    for (int cp = 0; cp < c; ++cp) {
        const size_t off = (((size_t)(b * NCH + cp) * DI + d) << 4) + n;
        h = fmaf(Dprod[off], h, hend[off]);
    }

    const float4* dtp = (const float4*)(dtT + (size_t)d * ML + m0);
    const float4* xp  = (const float4*)(xT  + (size_t)d * ML + m0);
    const float4* Bp  = (const float4*)(bcT + (size_t)n * ML + m0);
    const float4* Cp  = (const float4*)(bcT + (size_t)(DST + n) * ML + m0);
    float4* yq = (float4*)(xT + (size_t)d * ML + m0);

    float4 dt4 = dtp[0], x4 = xp[0], B4 = Bp[0], C4 = Cp[0];

    for (int it = 0; it < CHL / 4; ++it) {
        const float4 dtc = dt4, xc4 = x4, Bc = B4, Cc = C4;
        if (it + 1 < CHL / 4) {
            dt4 = dtp[it + 1]; x4 = xp[it + 1];
            B4 = Bp[it + 1];   C4 = Cp[it + 1];
        }
        float4 y4;
#pragma unroll
        for (int i = 0; i < 4; ++i) {
            const float dtv = ((const float*)&dtc)[i];
            const float xv  = ((const float*)&xc4)[i];
            const float Bn  = ((const float*)&Bc)[i];
            const float Cn  = ((const float*)&Cc)[i];
            const float e = __expf(dtv * Anat);
            h = fmaf(e, h, dtv * xv * Bn);
            const float p = red16_(h * Cn);
            ((float*)&y4)[i] = fmaf(xv, dpd, p);
        }
        if (n == 0) yq[it] = y4;
    }
}

// ---------------------------------------------------------------------------
// Gate + transpose: y_bf16[m][d] = bf16( yT[d][m] * zg[m][d] ).
// ---------------------------------------------------------------------------
__global__ __launch_bounds__(256) void gate_transpose_kernel(
    const float* __restrict__ yT,       // [DI][ML]
    const float* __restrict__ zg,       // [ML][DI]  (silu already applied)
    unsigned short* __restrict__ yb)    // [ML][DI] bf16
{
    __shared__ float Ty[64][65];
    __shared__ float Tz[64][65];
    const int d0 = blockIdx.x * 64;
    const int m0 = blockIdx.y * 64;
    const int t  = threadIdx.x;
    const int cc = t & 63, r4 = t >> 6;

#pragma unroll 4
    for (int rr = 0; rr < 16; ++rr) {
        const int r = rr * 4 + r4;
        Ty[r][cc] = yT[(size_t)(d0 + r) * ML + m0 + cc];
        Tz[r][cc] = zg[(size_t)(m0 + r) * DI + d0 + cc];
    }
    __syncthreads();

    const int dp  = (t & 31) * 2;
    const int mr4 = t >> 5;
#pragma unroll 4
    for (int rr = 0; rr < 8; ++rr) {
        const int mr = rr * 8 + mr4;
        const float v0 = Ty[dp][mr]     * Tz[mr][dp];
        const float v1 = Ty[dp + 1][mr] * Tz[mr][dp + 1];
        *(unsigned int*)(yb + (size_t)(m0 + mr) * DI + d0 + dp) =
            (unsigned int)pk_bf16(v0, v1);
    }
}

// ---------------------------------------------------------------------------
extern "C" void kernel_launch(void* const* d_in, const int* in_sizes, int n_in,
                              void* d_out, int out_size, void* d_ws, size_t ws_size,
                              hipStream_t stream)
{
    const float* x      = (const float*)d_in[0];
    const float* W_in   = (const float*)d_in[1];
    const float* conv_w = (const float*)d_in[2];
    const float* conv_b = (const float*)d_in[3];
    const float* W_x    = (const float*)d_in[4];
    const float* W_dt   = (const float*)d_in[5];
    const float* b_dt   = (const float*)d_in[6];
    const float* A_log  = (const float*)d_in[7];
    const float* Dp     = (const float*)d_in[8];
    const float* W_out  = (const float*)d_in[9];
    float* out = (float*)d_out;

    // workspace (proven 48.75 MB footprint):
    float* ws     = (float*)d_ws;
    float* xc_arr = ws;                         // 16 MB: xc -> splitK part -> dtT -> {ybf 8MB | wobf 4MB}
    float* zg_arr = xc_arr + (size_t)ML * DI;   // 16 MB: silu(z); later outGEMM partials 0-1
    float* xT_arr = zg_arr + (size_t)ML * DI;   // 16 MB: {xbf|wibf} -> xT[d][m] -> yT; later partials 2-3
    float* dtlow  = xT_arr + (size_t)ML * DI;   // 0.5 MB: x_dbl[:, :64]
    float* bcT    = dtlow  + (size_t)ML * DTR;  // 0.25 MB: B/C transposed [32][ML]

    // d_out scratch (dead until out-GEMM reduce): 4 + 4 = 8 MB
    float* hend  = out;                                   // [Bb*NCH*DI*16] 4 MB
    float* Dprod = hend + (size_t)Bb * NCH * DI * DST;    // 4 MB

    // bf16 staging buffers
    unsigned short* xbf  = (unsigned short*)xT_arr;            // 4 MB
    unsigned short* wibf = xbf + (size_t)ML * DM;              // 8 MB
    float* dtT = xc_arr;                                       // [DI][ML]
    unsigned short* ybf  = (unsigned short*)xc_arr;            // 8 MB
    unsigned short* wobf = (unsigned short*)xc_arr + (size_t)ML * DI;  // 4 MB
    float* oPart = zg_arr;   // out-GEMM split-K partials: 4 x 8 MB

    const dim3 blk(256);

    // 0) convert x, W_in to bf16 (into xT region, dead until conv)
    cvt_bf16_kernel<<<dim3(ML * DM / 4 / 256), blk, 0, stream>>>(
        x, xbf, ML * DM / 4);
    cvt_bf16_kernel<<<dim3(DXZ * DM / 4 / 256), blk, 0, stream>>>(
        W_in, wibf, DXZ * DM / 4);

    // 1) in-proj: xc | silu(z) = x @ W_in^T   (bf16 MFMA, both operands bf16)
    gemm_bf16_f32in<1, 1, 1><<<dim3(DXZ / 128, ML / 128), blk, 0, stream>>>(
        xbf, DM, wibf, DM, xc_arr, zg_arr, DI, DM, 0, 0, 0);

    // 2) depthwise causal conv + silu, transposed -> xT[d][m]
    conv_transpose_kernel<<<dim3(DI / 32, ML / 256), blk, 0, stream>>>(
        xc_arr, conv_w, conv_b, xT_arr);

    // 3) x_dbl partials = x @ W_x^T from xT (ATRANS, split-K x8) -> xc (dead)
    gemm_nt<0, 1><<<dim3(1, ML / 128, 8), blk, 0, stream>>>(
        xT_arr, ML, W_x, DI, xc_arr, 768, DXD, DI / 8, nullptr,
        (DI / 8) * ML, DI / 8, DXD);
    reduce_xdbl_kernel<<<dim3((ML * DXD + 255) / 256), blk, 0, stream>>>(
        xc_arr, dtlow, bcT);

    // 4) dt_T = softplus(W_dt @ dtlow^T + b_dt[row])  [DI][ML] over xc
    gemm_nt<2, 0><<<dim3(ML / 128, DI / 128), blk, 0, stream>>>(
        W_dt, DTR, dtlow, DTR, dtT, ML, ML, DTR, b_dt, 0, 0, 0);

    // 5) chunked selective scan; pass2 writes ungated yT in-place over xT
    scan_pass1<<<dim3(DI / 16, NCH - 1, Bb), blk, 0, stream>>>(
        dtT, xT_arr, bcT, A_log, hend, Dprod);
    scan_pass2<<<dim3(DI / 16, NCH, Bb), blk, 0, stream>>>(
        dtT, xT_arr, bcT, A_log, Dp, hend, Dprod);

    // 6) gate + transpose -> ybf; convert W_out -> bf16 (dtT dead now)
    gate_transpose_kernel<<<dim3(DI / 64, ML / 64), blk, 0, stream>>>(
        xT_arr, zg_arr, ybf);
    cvt_bf16_kernel<<<dim3(DM * DI / 4 / 256), blk, 0, stream>>>(
        W_out, wobf, DM * DI / 4);

    // 7) out partials = ybf @ wobf^T  (bf16 MFMA, split-K x4) -> zg/xT (dead)
    gemm_bf16_f32in<0, 1, 1><<<dim3(DM / 128, ML / 128, 4), blk, 0, stream>>>(
        ybf, DI, wobf, DI, oPart, nullptr, DM, DI / 4,
        DI / 4, DI / 4, (long)ML * DM);

    // 8) out = sum of 4 partials
    reduce4_kernel<<<dim3((ML * DM / 4 + 255) / 256), blk, 0, stream>>>(
        oPart, out, ML * DM / 4);
}